// Round 6
// baseline (367.959 us; speedup 1.0000x reference)
//
#include <hip/hip_runtime.h>

typedef unsigned short u16;
typedef __bf16 bf16x8 __attribute__((ext_vector_type(8)));
typedef float f32x4 __attribute__((ext_vector_type(4)));
typedef u16 u16x8 __attribute__((ext_vector_type(8)));
typedef u16 u16x4 __attribute__((ext_vector_type(4)));

#define MFMA16(a, b, c) __builtin_amdgcn_mfma_f32_16x16x32_bf16(a, b, c, 0, 0, 0)

static constexpr float QSC = 0.18033688011112042f;  // 0.125 * log2(e)

__device__ inline u16 f2bf(float f) {
  union { float f; unsigned u; } x; x.f = f;
  unsigned r = x.u + 0x7FFF + ((x.u >> 16) & 1);  // RNE
  return (u16)(r >> 16);
}
__device__ inline u16 cvt_bf(float f) {  // native, pairs into v_cvt_pk_bf16_f32
  __bf16 h = (__bf16)f; return __builtin_bit_cast(u16, h);
}
__device__ inline bf16x8 ld_frag(const u16* p) {
  return __builtin_bit_cast(bf16x8, *(const u16x8*)p);
}
__device__ inline void dma16(const u16* g, u16* l) {
  __builtin_amdgcn_global_load_lds(
      (const __attribute__((address_space(1))) unsigned*)g,
      (__attribute__((address_space(3))) unsigned*)l, 16, 0, 0);
}

#if __has_builtin(__builtin_amdgcn_exp2f)
#define EXP2(x) __builtin_amdgcn_exp2f(x)
#else
#define EXP2(x) exp2f(x)
#endif

// ---------------------------------------------------------------------------
// Weight transpose-convert: W[k][n] fp32 -> Wt[n][k] bf16. z selects weight.
// ---------------------------------------------------------------------------
__launch_bounds__(256)
__global__ void prep_w(const float* __restrict__ Wq, const float* __restrict__ Wk,
                       const float* __restrict__ Wv, const float* __restrict__ Wo,
                       u16* __restrict__ Wt) {
  __shared__ u16 T[64 * 72];
  const int z = blockIdx.z;
  const float* W = z == 0 ? Wq : z == 1 ? Wk : z == 2 ? Wv : Wo;
  u16* D = Wt + ((size_t)z << 20);
  const int k0 = blockIdx.y * 64, c0 = blockIdx.x * 64;
  const int tid = threadIdx.x;
  const int kr = tid >> 2, cs = (tid & 3) * 16;
  const float* src = W + (size_t)(k0 + kr) * 1024 + c0 + cs;
  float f[16];
#pragma unroll
  for (int i = 0; i < 4; ++i) *(float4*)&f[i * 4] = ((const float4*)src)[i];
#pragma unroll
  for (int i = 0; i < 16; ++i) T[(cs + i) * 72 + kr] = cvt_bf(f[i]);
  __syncthreads();
  const int nn = tid >> 2, ks = (tid & 3) * 16;
  u16* dst = D + (size_t)(c0 + nn) * 1024 + k0 + ks;
  *(u16x8*)dst = *(u16x8*)&T[nn * 72 + ks];
  *(u16x8*)(dst + 8) = *(u16x8*)&T[nn * 72 + ks + 8];
}

// ---------------------------------------------------------------------------
// Input convert: fp32 -> bf16 row-major. z selects tensor (8Mi elems each).
// ---------------------------------------------------------------------------
__launch_bounds__(256)
__global__ void prep_a(const float* __restrict__ q, const float* __restrict__ k,
                       const float* __restrict__ v, u16* __restrict__ dq,
                       u16* __restrict__ dk, u16* __restrict__ dv) {
  const int z = blockIdx.z;
  const float* s = z == 0 ? q : z == 1 ? k : v;
  u16* d = z == 0 ? dq : z == 1 ? dk : dv;
  for (size_t i = blockIdx.x * 256 + threadIdx.x; i < (size_t)1048576; i += 262144) {
    const float* g = s + i * 8;
    float4 f0 = *(const float4*)g, f1 = *(const float4*)(g + 4);
    u16x8 h;
    h[0] = cvt_bf(f0.x); h[1] = cvt_bf(f0.y); h[2] = cvt_bf(f0.z); h[3] = cvt_bf(f0.w);
    h[4] = cvt_bf(f1.x); h[5] = cvt_bf(f1.y); h[6] = cvt_bf(f1.z); h[7] = cvt_bf(f1.w);
    *(u16x8*)(d + i * 8) = h;
  }
}

// ---------------------------------------------------------------------------
// QKV GEMM — 256x128 tile, BK=32, 4 waves (2M x 2N, per-wave 128x64 out).
// Same verified 2-phase schedule as the R4 256x256 kernel (per-wave ds_read /
// MFMA counts identical); tile halved in N so that:
//   - regs/block halve -> 2 blocks/CU resident (R4's 256x256 was 1/CU:
//     ~100 VGPR + 128 acc-AGPR = 256-granule -> 8 waves/CU);
//   - grid = 32m x 8n x 3z = 768 blocks = EXACTLY 3 per CU -> zero partial
//     round (R4's 384 at 1/CU ran 256 + half-empty 128 = 24% idle).
// 2-phase K-step: {stage A(t+1)(4 dma) || ds_read b,a[0..3] || 16 MFMA || bar}
//                 {stage B(t+1)(2 dma) || ds_read a[4..7]   || 16 MFMA ||
//                  vmcnt(0)+bar}   (dual 24KB buffers; drain-at-boundary —
//                  counted-vmcnt triple-buf variant measured SLOWER, R5).
// LDS chunked linear: A chunk c=[kc(4)][row(256)] at c*8; B at 8192+c*8.
// z=0: Q=relu*QSC token-major; z=1: K token-major;
// z=2: operand-swapped (A=Wt feature-rows, B=Av token-rows) -> acc = V^T,
//      repacked via 64KB LDS to Vt[b*1024 + feat][token] in one pass.
// ---------------------------------------------------------------------------
__launch_bounds__(256, 2)
__global__ void gemm_fwd(const u16* __restrict__ Aq, const u16* __restrict__ Ak,
                         const u16* __restrict__ Av, const u16* __restrict__ Wt,
                         u16* __restrict__ Qw, u16* __restrict__ Kw,
                         u16* __restrict__ Vw) {
  __shared__ u16 smem[32768];  // staging: 2 bufs x 12288 u16 (A 8192 | B 4096);
                               // z=2 repack reuses all 64KB
  const int z = blockIdx.z;
  const u16* A = z == 0 ? Aq : z == 1 ? Ak : Av;
  const u16* Bt = Wt + ((size_t)z << 20);
  u16* out = z == 0 ? Qw : z == 1 ? Kw : Vw;
  const u16* Aop = (z == 2) ? Bt : A;
  const u16* Bop = (z == 2) ? A : Bt;

  const int tid = threadIdx.x;
  const int lane = tid & 63, l15 = lane & 15, quad = lane >> 4;
  const int wv = tid >> 6, wm = wv & 1, wn = wv >> 1;  // 2M x 2N wave grid
  int m0, n0;
  if (z == 2) {
    const int id = blockIdx.y * 32 + blockIdx.x;  // 256 blocks per z
    m0 = (id >> 6) * 256;   // 4 feature tiles
    n0 = (id & 63) * 128;   // 64 token tiles
  } else {
    // XCD-contiguous remap of the 32-wide m dim (bx fastest in dispatch order)
    const int mblk = ((blockIdx.x & 7) << 2) | (blockIdx.x >> 3);
    m0 = mblk * 256;
    n0 = blockIdx.y * 128;
  }

  // Staging sources: A chunk c = i*256+tid -> row=tid, kc=i (i=0..3);
  //                  B chunk c = i*256+tid -> row=tid&127, kc=i*2+(tid>>7).
  const u16* gA[4];
#pragma unroll
  for (int i = 0; i < 4; ++i) gA[i] = Aop + (size_t)(m0 + tid) * 1024 + i * 8;
  const u16* gB[2];
#pragma unroll
  for (int i = 0; i < 2; ++i)
    gB[i] = Bop + (size_t)(n0 + (tid & 127)) * 1024 + (i * 2 + (tid >> 7)) * 8;

  const int offA = (quad * 256 + wm * 128 + l15) * 8;        // + mi*128
  const int offB = 8192 + (quad * 128 + wn * 64 + l15) * 8;  // + nj*128

  f32x4 acc[8][4] = {};

  // Prologue: stage tile 0 -> buf0 (6 dma/thread), drain, barrier.
#pragma unroll
  for (int i = 0; i < 4; ++i) dma16(gA[i], &smem[i * 2048 + wv * 512]);
#pragma unroll
  for (int i = 0; i < 2; ++i) dma16(gB[i], &smem[8192 + i * 2048 + wv * 512]);
  asm volatile("s_waitcnt vmcnt(0)" ::: "memory");
  __builtin_amdgcn_sched_barrier(0);
  __builtin_amdgcn_s_barrier();

#pragma unroll 1
  for (int t = 0; t < 32; ++t) {
    const int bo = (t & 1) ? 12288 : 0;
    const int nbo = (t & 1) ? 0 : 12288;
    // ---- phase 0: stage A(t+1); read b[0..3], a[0..3]; 16 MFMA ----
    if (t + 1 < 32) {
#pragma unroll
      for (int i = 0; i < 4; ++i)
        dma16(gA[i] + (t + 1) * 32, &smem[nbo + i * 2048 + wv * 512]);
    }
    bf16x8 a[4], b[4];
#pragma unroll
    for (int j = 0; j < 4; ++j) b[j] = ld_frag(&smem[bo + offB + j * 128]);
#pragma unroll
    for (int i = 0; i < 4; ++i) a[i] = ld_frag(&smem[bo + offA + i * 128]);
    asm volatile("s_waitcnt lgkmcnt(0)" ::: "memory");
    __builtin_amdgcn_sched_barrier(0);
    __builtin_amdgcn_s_setprio(1);
#pragma unroll
    for (int i = 0; i < 4; ++i)
#pragma unroll
      for (int j = 0; j < 4; ++j)
        acc[i][j] = MFMA16(a[i], b[j], acc[i][j]);
    __builtin_amdgcn_s_setprio(0);
    __builtin_amdgcn_s_barrier();
    // ---- phase 1: stage B(t+1); read a[4..7]; 16 MFMA ----
    if (t + 1 < 32) {
#pragma unroll
      for (int i = 0; i < 2; ++i)
        dma16(gB[i] + (t + 1) * 32, &smem[nbo + 8192 + i * 2048 + wv * 512]);
    }
#pragma unroll
    for (int i = 0; i < 4; ++i) a[i] = ld_frag(&smem[bo + offA + (4 + i) * 128]);
    asm volatile("s_waitcnt lgkmcnt(0)" ::: "memory");
    __builtin_amdgcn_sched_barrier(0);
    __builtin_amdgcn_s_setprio(1);
#pragma unroll
    for (int i = 0; i < 4; ++i)
#pragma unroll
      for (int j = 0; j < 4; ++j)
        acc[4 + i][j] = MFMA16(a[i], b[j], acc[4 + i][j]);
    __builtin_amdgcn_s_setprio(0);
    // ---- step boundary: tile t+1 must have landed before next ds_reads ----
    if (t + 1 < 32) {
      asm volatile("s_waitcnt vmcnt(0)" ::: "memory");
      __builtin_amdgcn_sched_barrier(0);
    }
    __builtin_amdgcn_s_barrier();
  }

  if (z < 2) {
    const float sc = z == 0 ? QSC : 1.0f;
#pragma unroll
    for (int i = 0; i < 8; ++i)
#pragma unroll
      for (int j = 0; j < 4; ++j)
#pragma unroll
        for (int r = 0; r < 4; ++r) {
          float v = fmaxf(acc[i][j][r], 0.f) * sc;
          int m = m0 + wm * 128 + i * 16 + quad * 4 + r;
          int n = n0 + wn * 64 + j * 16 + l15;
          out[(size_t)m * 1024 + n] = f2bf(v);
        }
  } else {
    // acc = V^T tile: row = feature (m0+...), col = token (n0+...).
    // Repack through LDS [feat 256][tok 128] (64KB, single pass), then
    // coalesced u16x8 stores to Vt[b*1024 + feat][token].
    const int bb = n0 >> 11, s0 = n0 & 2047;
    __syncthreads();
#pragma unroll
    for (int i = 0; i < 8; ++i)
#pragma unroll
      for (int j = 0; j < 4; ++j)
#pragma unroll
        for (int r = 0; r < 4; ++r) {
          const int row = wm * 128 + i * 16 + quad * 4 + r;
          const int col = wn * 64 + j * 16 + l15;
          smem[row * 128 + col] = f2bf(fmaxf(acc[i][j][r], 0.f));
        }
    __syncthreads();
#pragma unroll
    for (int i2 = 0; i2 < 16; ++i2) {
      const int c = i2 * 256 + tid;
      const int row = c >> 4, ch = c & 15;
      u16* dst = out + (size_t)(bb * 1024 + m0 + row) * 2048 + s0 + ch * 8;
      *(u16x8*)dst = *(u16x8*)&smem[row * 128 + ch * 8];
    }
  }
}

// ---------------------------------------------------------------------------
// Output GEMM: relu(ctx @ Wo), fp32 out — same 256x128 4-wave 2-phase
// template as gemm_fwd.  Grid 32x8 = 256 blocks = 1/CU, all resident.
// ---------------------------------------------------------------------------
__launch_bounds__(256, 2)
__global__ void gemm_out(const u16* __restrict__ A, const u16* __restrict__ Bt,
                         float* __restrict__ out) {
  __shared__ u16 smem[24576];  // 2 bufs x 12288 u16 (A 8192 | B 4096)
  const int tid = threadIdx.x;
  const int lane = tid & 63, l15 = lane & 15, quad = lane >> 4;
  const int wv = tid >> 6, wm = wv & 1, wn = wv >> 1;
  const int mblk = ((blockIdx.x & 7) << 2) | (blockIdx.x >> 3);
  const int m0 = mblk * 256;
  const int n0 = blockIdx.y * 128;

  const u16* gA[4];
#pragma unroll
  for (int i = 0; i < 4; ++i) gA[i] = A + (size_t)(m0 + tid) * 1024 + i * 8;
  const u16* gB[2];
#pragma unroll
  for (int i = 0; i < 2; ++i)
    gB[i] = Bt + (size_t)(n0 + (tid & 127)) * 1024 + (i * 2 + (tid >> 7)) * 8;

  const int offA = (quad * 256 + wm * 128 + l15) * 8;
  const int offB = 8192 + (quad * 128 + wn * 64 + l15) * 8;

  f32x4 acc[8][4] = {};

#pragma unroll
  for (int i = 0; i < 4; ++i) dma16(gA[i], &smem[i * 2048 + wv * 512]);
#pragma unroll
  for (int i = 0; i < 2; ++i) dma16(gB[i], &smem[8192 + i * 2048 + wv * 512]);
  asm volatile("s_waitcnt vmcnt(0)" ::: "memory");
  __builtin_amdgcn_sched_barrier(0);
  __builtin_amdgcn_s_barrier();

#pragma unroll 1
  for (int t = 0; t < 32; ++t) {
    const int bo = (t & 1) ? 12288 : 0;
    const int nbo = (t & 1) ? 0 : 12288;
    if (t + 1 < 32) {
#pragma unroll
      for (int i = 0; i < 4; ++i)
        dma16(gA[i] + (t + 1) * 32, &smem[nbo + i * 2048 + wv * 512]);
    }
    bf16x8 a[4], b[4];
#pragma unroll
    for (int j = 0; j < 4; ++j) b[j] = ld_frag(&smem[bo + offB + j * 128]);
#pragma unroll
    for (int i = 0; i < 4; ++i) a[i] = ld_frag(&smem[bo + offA + i * 128]);
    asm volatile("s_waitcnt lgkmcnt(0)" ::: "memory");
    __builtin_amdgcn_sched_barrier(0);
    __builtin_amdgcn_s_setprio(1);
#pragma unroll
    for (int i = 0; i < 4; ++i)
#pragma unroll
      for (int j = 0; j < 4; ++j)
        acc[i][j] = MFMA16(a[i], b[j], acc[i][j]);
    __builtin_amdgcn_s_setprio(0);
    __builtin_amdgcn_s_barrier();
    if (t + 1 < 32) {
#pragma unroll
      for (int i = 0; i < 2; ++i)
        dma16(gB[i] + (t + 1) * 32, &smem[nbo + 8192 + i * 2048 + wv * 512]);
    }
#pragma unroll
    for (int i = 0; i < 4; ++i) a[i] = ld_frag(&smem[bo + offA + (4 + i) * 128]);
    asm volatile("s_waitcnt lgkmcnt(0)" ::: "memory");
    __builtin_amdgcn_sched_barrier(0);
    __builtin_amdgcn_s_setprio(1);
#pragma unroll
    for (int i = 0; i < 4; ++i)
#pragma unroll
      for (int j = 0; j < 4; ++j)
        acc[4 + i][j] = MFMA16(a[i], b[j], acc[4 + i][j]);
    __builtin_amdgcn_s_setprio(0);
    if (t + 1 < 32) {
      asm volatile("s_waitcnt vmcnt(0)" ::: "memory");
      __builtin_amdgcn_sched_barrier(0);
    }
    __builtin_amdgcn_s_barrier();
  }

#pragma unroll
  for (int i = 0; i < 8; ++i)
#pragma unroll
    for (int j = 0; j < 4; ++j)
#pragma unroll
      for (int r = 0; r < 4; ++r) {
        int m = m0 + wm * 128 + i * 16 + quad * 4 + r;
        int n = n0 + wn * 64 + j * 16 + l15;
        out[(size_t)m * 1024 + n] = fmaxf(acc[i][j][r], 0.f);
      }
}

// ---------------------------------------------------------------------------
// Flash attention v9 — 64 q rows per wave (qh=4), 256 q per block.
// Grid (64,8) = 512 blocks = exactly 2/CU, both resident (64KB LDS)
// -> zero tail.  Per-FLOP LDS traffic cut 29% vs v8 (K/V frag reads amortized
// over 2x q rows).  Same verified layouts; strides widened for 64-q P buffer.
// ---------------------------------------------------------------------------
__launch_bounds__(256, 2)
__global__ void attn(const u16* __restrict__ Q, const u16* __restrict__ K,
                     const u16* __restrict__ V, u16* __restrict__ ctx) {
  __shared__ u16 Ksm[2][4096];  // chunks [dc(8)][key(64)] x 8 u16 (8KB/buf)
  __shared__ u16 Vsm[2][4096];  // chunks [kc(8)][d(64)]  x 8 u16
  __shared__ u16 Psm[4][4096];  // per-wave chunks [kc(8)][q(64)] x 8 u16

  const int tid = threadIdx.x;
  const int lane = tid & 63, l15 = lane & 15, quad = lane >> 4;
  const int wv = tid >> 6;
  const int bh = blockIdx.x, b = bh >> 4, h = bh & 15;
  const int q0 = blockIdx.y * 256 + wv * 64;

  const u16* Kb = K + ((size_t)b * 2048) * 1024 + h * 64;
  const u16* Vb = V + (size_t)bh * 64 * 2048;
  u16* Pw = Psm[wv];

  // Per-thread DMA sources. Chunk id c = issue*256+tid covers 512 chunks/tensor:
  // K: key = c&63 (row, token-major), dc = c>>6  -> LDS [dc][key]
  // V: d   = c&63 (row, [d][s] layout), kc = c>>6 -> LDS [kc][d]
  const int ck0 = tid, ck1 = 256 + tid;
  const u16* kg0 = Kb + (size_t)(ck0 & 63) * 1024 + (ck0 >> 6) * 8;
  const u16* kg1 = Kb + (size_t)(ck1 & 63) * 1024 + (ck1 >> 6) * 8;
  const u16* vg0 = Vb + (size_t)(ck0 & 63) * 2048 + (ck0 >> 6) * 8;
  const u16* vg1 = Vb + (size_t)(ck1 & 63) * 2048 + (ck1 >> 6) * 8;

  // Q B-frags (pre-scaled by 0.125*log2e), resident all kernel (32 VGPR)
  bf16x8 aq[4][2];
#pragma unroll
  for (int qh = 0; qh < 4; ++qh)
#pragma unroll
    for (int kk = 0; kk < 2; ++kk)
      aq[qh][kk] = ld_frag(Q + (size_t)(b * 2048 + q0 + qh * 16 + l15) * 1024 +
                           h * 64 + kk * 32 + quad * 8);

  f32x4 o[4][4] = {};
  float ls[4] = {0.f, 0.f, 0.f, 0.f};

  // Prologue: DMA tile 0 -> buffer 0
  dma16(kg0, &Ksm[0][ck0 * 8]);
  dma16(kg1, &Ksm[0][ck1 * 8]);
  dma16(vg0, &Vsm[0][ck0 * 8]);
  dma16(vg1, &Vsm[0][ck1 * 8]);

#pragma unroll 1
  for (int t = 0; t < 32; ++t) {
    const int cur = t & 1, nxt = cur ^ 1;
    __syncthreads();  // drains tile-t DMA (vmcnt) + prior tile's LDS reads (WAR)

    if (t + 1 < 32) {  // DMA tile t+1 -> other buffer; consumed after NEXT barrier
      const int kadv = (t + 1) * 64;
      dma16(kg0 + (size_t)kadv * 1024, &Ksm[nxt][ck0 * 8]);
      dma16(kg1 + (size_t)kadv * 1024, &Ksm[nxt][ck1 * 8]);
      dma16(vg0 + kadv, &Vsm[nxt][ck0 * 8]);
      dma16(vg1 + kadv, &Vsm[nxt][ck1 * 8]);
    }

    // kf from LDS: A-frag [m=key=jj*16+l15][k=d=kk*32+quad*8]
    bf16x8 kf[2][4];
#pragma unroll
    for (int kk = 0; kk < 2; ++kk)
#pragma unroll
      for (int jj = 0; jj < 4; ++jj)
        kf[kk][jj] = ld_frag(&Ksm[cur][((kk * 4 + quad) * 64 + jj * 16 + l15) * 8]);

    // S^T = K·Q^T (col = q = l15, row = key = quad*4+r within 16-block jj)
    f32x4 st[4][4] = {};
    asm volatile("s_waitcnt lgkmcnt(0)" ::: "memory");
    __builtin_amdgcn_sched_barrier(0);
    __builtin_amdgcn_s_setprio(1);
#pragma unroll
    for (int kk = 0; kk < 2; ++kk)
#pragma unroll
      for (int jj = 0; jj < 4; ++jj)
#pragma unroll
        for (int qh = 0; qh < 4; ++qh)
          st[qh][jj] = MFMA16(kf[kk][jj], aq[qh][kk], st[qh][jj]);
    __builtin_amdgcn_s_setprio(0);

    // p = exp2(st); packed cvt; chunked conflict-free P write
#pragma unroll
    for (int qh = 0; qh < 4; ++qh)
#pragma unroll
      for (int jj = 0; jj < 4; ++jj) {
        float p0 = EXP2(st[qh][jj][0]), p1 = EXP2(st[qh][jj][1]);
        float p2 = EXP2(st[qh][jj][2]), p3 = EXP2(st[qh][jj][3]);
        ls[qh] += (p0 + p1) + (p2 + p3);
        u16x4 pk;
        pk[0] = cvt_bf(p0); pk[1] = cvt_bf(p1);
        pk[2] = cvt_bf(p2); pk[3] = cvt_bf(p3);
        const int kc = jj * 2 + (quad >> 1);
        *(u16x4*)&Pw[(kc * 64 + qh * 16 + l15) * 8 + (quad & 1) * 4] = pk;
      }

    // pa (B-frag of P^T) and vb (A-frag of V^T) from LDS; PV MFMAs
#pragma unroll
    for (int kk = 0; kk < 2; ++kk) {
      bf16x8 pa[4];
#pragma unroll
      for (int qh = 0; qh < 4; ++qh)
        pa[qh] = ld_frag(&Pw[((kk * 4 + quad) * 64 + qh * 16 + l15) * 8]);
      asm volatile("s_waitcnt lgkmcnt(0)" ::: "memory");
      __builtin_amdgcn_sched_barrier(0);
      __builtin_amdgcn_s_setprio(1);
#pragma unroll
      for (int j = 0; j < 4; ++j) {
        bf16x8 vb = ld_frag(&Vsm[cur][((kk * 4 + quad) * 64 + j * 16 + l15) * 8]);
#pragma unroll
        for (int qh = 0; qh < 4; ++qh)
          o[qh][j] = MFMA16(vb, pa[qh], o[qh][j]);
      }
      __builtin_amdgcn_s_setprio(0);
    }
  }

  float inv[4];
#pragma unroll
  for (int qh = 0; qh < 4; ++qh) {
    ls[qh] += __shfl_xor(ls[qh], 16, 64);
    ls[qh] += __shfl_xor(ls[qh], 32, 64);
    inv[qh] = 1.f / ls[qh];
  }

  // O^T: row = d = j*16+quad*4+r, col = q = l15 -> 8B vector ctx stores
#pragma unroll
  for (int qh = 0; qh < 4; ++qh) {
    const int tok = b * 2048 + q0 + qh * 16 + l15;
#pragma unroll
    for (int j = 0; j < 4; ++j) {
      u16x4 pk;
#pragma unroll
      for (int r = 0; r < 4; ++r) pk[r] = cvt_bf(o[qh][j][r] * inv[qh]);
      *(u16x4*)&ctx[(size_t)tok * 1024 + h * 64 + j * 16 + quad * 4] = pk;
    }
  }
}

// ---------------------------------------------------------------------------
extern "C" void kernel_launch(void* const* d_in, const int* in_sizes, int n_in,
                              void* d_out, int out_size, void* d_ws, size_t ws_size,
                              hipStream_t stream) {
  const float* query = (const float*)d_in[0];
  const float* key   = (const float*)d_in[1];
  const float* value = (const float*)d_in[2];
  const float* Wq = (const float*)d_in[3];
  const float* Wk = (const float*)d_in[4];
  const float* Wv = (const float*)d_in[5];
  const float* Wo = (const float*)d_in[6];
  float* outp = (float*)d_out;

  // ws (u16 units): Wt 4Mi | Awq 8Mi | Qw 8Mi | Kw 8Mi | Vt 8Mi = 72 MB.
  // Awk/Awv live in d_out (32 MB, consumed before gemm_out overwrites it);
  // ctx aliases Awq (consumed by gemm_fwd before attn writes it).
  u16* Wt  = (u16*)d_ws;
  u16* Awq = Wt + ((size_t)4 << 20);
  u16* Qw  = Awq + ((size_t)8 << 20);
  u16* Kw  = Qw + ((size_t)8 << 20);
  u16* Vt  = Kw + ((size_t)8 << 20);
  u16* Awk = (u16*)d_out;
  u16* Awv = Awk + ((size_t)8 << 20);
  u16* Cw  = Awq;

  prep_w<<<dim3(16, 16, 4), 256, 0, stream>>>(Wq, Wk, Wv, Wo, Wt);
  prep_a<<<dim3(1024, 1, 3), 256, 0, stream>>>(query, key, value, Awq, Awk, Awv);
  gemm_fwd<<<dim3(32, 8, 3), 256, 0, stream>>>(Awq, Awk, Awv, Wt, Qw, Kw, Vt);
  attn<<<dim3(64, 8), 256, 0, stream>>>(Qw, Kw, Vt, Cw);
  gemm_out<<<dim3(32, 8), 256, 0, stream>>>(Cw, Wt + ((size_t)3 << 20), outp);
}

// Round 7
// 364.687 us; speedup vs baseline: 1.0090x; 1.0090x over previous
//
#include <hip/hip_runtime.h>

typedef unsigned short u16;
typedef __bf16 bf16x8 __attribute__((ext_vector_type(8)));
typedef float f32x4 __attribute__((ext_vector_type(4)));
typedef u16 u16x8 __attribute__((ext_vector_type(8)));
typedef u16 u16x4 __attribute__((ext_vector_type(4)));

#define MFMA16(a, b, c) __builtin_amdgcn_mfma_f32_16x16x32_bf16(a, b, c, 0, 0, 0)

static constexpr float QSC = 0.18033688011112042f;  // 0.125 * log2(e)

__device__ inline u16 f2bf(float f) {
  union { float f; unsigned u; } x; x.f = f;
  unsigned r = x.u + 0x7FFF + ((x.u >> 16) & 1);  // RNE
  return (u16)(r >> 16);
}
__device__ inline u16 cvt_bf(float f) {  // native, pairs into v_cvt_pk_bf16_f32
  __bf16 h = (__bf16)f; return __builtin_bit_cast(u16, h);
}
__device__ inline bf16x8 ld_frag(const u16* p) {
  return __builtin_bit_cast(bf16x8, *(const u16x8*)p);
}
__device__ inline void dma16(const u16* g, u16* l) {
  __builtin_amdgcn_global_load_lds(
      (const __attribute__((address_space(1))) unsigned*)g,
      (__attribute__((address_space(3))) unsigned*)l, 16, 0, 0);
}

#if __has_builtin(__builtin_amdgcn_exp2f)
#define EXP2(x) __builtin_amdgcn_exp2f(x)
#else
#define EXP2(x) exp2f(x)
#endif

// ---------------------------------------------------------------------------
// Weight transpose-convert: W[k][n] fp32 -> Wt[n][k] bf16. z selects weight.
// ---------------------------------------------------------------------------
__launch_bounds__(256)
__global__ void prep_w(const float* __restrict__ Wq, const float* __restrict__ Wk,
                       const float* __restrict__ Wv, const float* __restrict__ Wo,
                       u16* __restrict__ Wt) {
  __shared__ u16 T[64 * 72];
  const int z = blockIdx.z;
  const float* W = z == 0 ? Wq : z == 1 ? Wk : z == 2 ? Wv : Wo;
  u16* D = Wt + ((size_t)z << 20);
  const int k0 = blockIdx.y * 64, c0 = blockIdx.x * 64;
  const int tid = threadIdx.x;
  const int kr = tid >> 2, cs = (tid & 3) * 16;
  const float* src = W + (size_t)(k0 + kr) * 1024 + c0 + cs;
  float f[16];
#pragma unroll
  for (int i = 0; i < 4; ++i) *(float4*)&f[i * 4] = ((const float4*)src)[i];
#pragma unroll
  for (int i = 0; i < 16; ++i) T[(cs + i) * 72 + kr] = cvt_bf(f[i]);
  __syncthreads();
  const int nn = tid >> 2, ks = (tid & 3) * 16;
  u16* dst = D + (size_t)(c0 + nn) * 1024 + k0 + ks;
  *(u16x8*)dst = *(u16x8*)&T[nn * 72 + ks];
  *(u16x8*)(dst + 8) = *(u16x8*)&T[nn * 72 + ks + 8];
}

// ---------------------------------------------------------------------------
// Input convert: fp32 -> bf16 row-major. z selects tensor (8Mi elems each).
// ---------------------------------------------------------------------------
__launch_bounds__(256)
__global__ void prep_a(const float* __restrict__ q, const float* __restrict__ k,
                       const float* __restrict__ v, u16* __restrict__ dq,
                       u16* __restrict__ dk, u16* __restrict__ dv) {
  const int z = blockIdx.z;
  const float* s = z == 0 ? q : z == 1 ? k : v;
  u16* d = z == 0 ? dq : z == 1 ? dk : dv;
  for (size_t i = blockIdx.x * 256 + threadIdx.x; i < (size_t)1048576; i += 262144) {
    const float* g = s + i * 8;
    float4 f0 = *(const float4*)g, f1 = *(const float4*)(g + 4);
    u16x8 h;
    h[0] = cvt_bf(f0.x); h[1] = cvt_bf(f0.y); h[2] = cvt_bf(f0.z); h[3] = cvt_bf(f0.w);
    h[4] = cvt_bf(f1.x); h[5] = cvt_bf(f1.y); h[6] = cvt_bf(f1.z); h[7] = cvt_bf(f1.w);
    *(u16x8*)(d + i * 8) = h;
  }
}

// ---------------------------------------------------------------------------
// QKV GEMM — 256x256 tile, BK=64, 8 waves (2M x 4N, per-wave 128x64 out).
// 128KB double-buffered LDS (A 32KB | B 32KB per buf).  This is the T3
// "minimum 2-phase" shape with HALVED step count vs the BK=32 version:
//   per step: {stage A(t+1) || ds_read kk0 || 32 MFMA ||
//              stage B(t+1) || ds_read kk1 || 32 MFMA || vmcnt(0) || 1 barrier}
// -> per MFMA: barriers/4, drains/2, ds_reads/2 vs the 99us BK=32 kernel.
// Occupancy unchanged (reg-pinned at 1 block/CU: 128 acc-AGPR + ~110 VGPR;
// transient liveness kept at a[4]+b[4] via two 16-MFMA sub-clusters per kk).
// LDS chunked linear: chunk c(16B) = [kc=c>>8][row=c&255] at c*8 -> both
// gload_lds dests (wave-uniform + lane*16B) and frag ds_read_b128 (16
// consecutive chunks per l15) conflict-free by construction.
// z=0: Q=relu*QSC token-major; z=1: K token-major;
// z=2: operand-swapped (A=Wt feature-rows, B=Av token-rows) -> acc = V^T,
//      repacked via LDS to Vt[b*1024 + feat][token].
// ---------------------------------------------------------------------------
__launch_bounds__(512, 2)
__global__ void gemm_fwd(const u16* __restrict__ Aq, const u16* __restrict__ Ak,
                         const u16* __restrict__ Av, const u16* __restrict__ Wt,
                         u16* __restrict__ Qw, u16* __restrict__ Kw,
                         u16* __restrict__ Vw) {
  __shared__ u16 smem[65536];  // 128KB: 2 bufs x (A 16384 u16 | B 16384 u16)
  const int z = blockIdx.z;
  const u16* A = z == 0 ? Aq : z == 1 ? Ak : Av;
  const u16* Bt = Wt + ((size_t)z << 20);
  u16* out = z == 0 ? Qw : z == 1 ? Kw : Vw;
  const u16* Aop = (z == 2) ? Bt : A;
  const u16* Bop = (z == 2) ? A : Bt;

  const int tid = threadIdx.x;
  const int lane = tid & 63, l15 = lane & 15, quad = lane >> 4;
  const int wv = tid >> 6, wm = wv & 1, wn = wv >> 1;  // 2M x 4N wave grid
  // XCD-contiguous remap of the 32-wide dim (bx fastest in dispatch order)
  const int mblk = ((blockIdx.x & 7) << 2) | (blockIdx.x >> 3);
  const int m0 = (z == 2) ? blockIdx.y * 256 : mblk * 256;
  const int n0 = (z == 2) ? mblk * 256 : blockIdx.y * 256;

  // Staging: chunk c = i*512+tid -> row=c&255, kc=c>>8 (kc 0..7 over BK=64).
  // LDS chunk index == c, dest = buf + c*8 (linear, wave-uniform + lane*16B).
  const u16* gA[4];
  const u16* gB[4];
#pragma unroll
  for (int i = 0; i < 4; ++i) {
    const int c = i * 512 + tid;
    gA[i] = Aop + (size_t)(m0 + (c & 255)) * 1024 + (c >> 8) * 8;
    gB[i] = Bop + (size_t)(n0 + (c & 255)) * 1024 + (c >> 8) * 8;
  }

  // Frag bases: kk selects k-half (chunk group stride 4*256*8 = 8192 u16).
  const int offA = (quad * 256 + wm * 128 + l15) * 8;          // + mi*128, +8192 for kk1
  const int offB = 16384 + (quad * 256 + wn * 64 + l15) * 8;   // + nj*128, +8192 for kk1

  f32x4 acc[8][4] = {};

  // Prologue: stage tile 0 -> buf0 (8 dma/thread), drain, barrier.
#pragma unroll
  for (int i = 0; i < 4; ++i) dma16(gA[i], &smem[i * 4096 + wv * 512]);
#pragma unroll
  for (int i = 0; i < 4; ++i) dma16(gB[i], &smem[16384 + i * 4096 + wv * 512]);
  asm volatile("s_waitcnt vmcnt(0)" ::: "memory");
  __builtin_amdgcn_sched_barrier(0);
  __builtin_amdgcn_s_barrier();

#pragma unroll 1
  for (int t = 0; t < 16; ++t) {
    const int bo = (t & 1) ? 32768 : 0;
    const int nbo = bo ^ 32768;
    bf16x8 a[4], b[4];
    // ---- kk=0: stage A(t+1); two 16-MFMA sub-clusters ----
    if (t < 15) {
#pragma unroll
      for (int i = 0; i < 4; ++i)
        dma16(gA[i] + (t + 1) * 64, &smem[nbo + i * 4096 + wv * 512]);
    }
#pragma unroll
    for (int j = 0; j < 4; ++j) b[j] = ld_frag(&smem[bo + offB + j * 128]);
#pragma unroll
    for (int i = 0; i < 4; ++i) a[i] = ld_frag(&smem[bo + offA + i * 128]);
    asm volatile("s_waitcnt lgkmcnt(0)" ::: "memory");
    __builtin_amdgcn_sched_barrier(0);
    __builtin_amdgcn_s_setprio(1);
#pragma unroll
    for (int i = 0; i < 4; ++i)
#pragma unroll
      for (int j = 0; j < 4; ++j)
        acc[i][j] = MFMA16(a[i], b[j], acc[i][j]);
    __builtin_amdgcn_s_setprio(0);
#pragma unroll
    for (int i = 0; i < 4; ++i)
      a[i] = ld_frag(&smem[bo + offA + (4 + i) * 128]);
    asm volatile("s_waitcnt lgkmcnt(0)" ::: "memory");
    __builtin_amdgcn_sched_barrier(0);
    __builtin_amdgcn_s_setprio(1);
#pragma unroll
    for (int i = 0; i < 4; ++i)
#pragma unroll
      for (int j = 0; j < 4; ++j)
        acc[4 + i][j] = MFMA16(a[i], b[j], acc[4 + i][j]);
    __builtin_amdgcn_s_setprio(0);
    // ---- kk=1: stage B(t+1); two 16-MFMA sub-clusters ----
    if (t < 15) {
#pragma unroll
      for (int i = 0; i < 4; ++i)
        dma16(gB[i] + (t + 1) * 64, &smem[nbo + 16384 + i * 4096 + wv * 512]);
    }
#pragma unroll
    for (int j = 0; j < 4; ++j)
      b[j] = ld_frag(&smem[bo + offB + 8192 + j * 128]);
#pragma unroll
    for (int i = 0; i < 4; ++i)
      a[i] = ld_frag(&smem[bo + offA + 8192 + i * 128]);
    asm volatile("s_waitcnt lgkmcnt(0)" ::: "memory");
    __builtin_amdgcn_sched_barrier(0);
    __builtin_amdgcn_s_setprio(1);
#pragma unroll
    for (int i = 0; i < 4; ++i)
#pragma unroll
      for (int j = 0; j < 4; ++j)
        acc[i][j] = MFMA16(a[i], b[j], acc[i][j]);
    __builtin_amdgcn_s_setprio(0);
#pragma unroll
    for (int i = 0; i < 4; ++i)
      a[i] = ld_frag(&smem[bo + offA + 8192 + (4 + i) * 128]);
    asm volatile("s_waitcnt lgkmcnt(0)" ::: "memory");
    __builtin_amdgcn_sched_barrier(0);
    __builtin_amdgcn_s_setprio(1);
#pragma unroll
    for (int i = 0; i < 4; ++i)
#pragma unroll
      for (int j = 0; j < 4; ++j)
        acc[4 + i][j] = MFMA16(a[i], b[j], acc[4 + i][j]);
    __builtin_amdgcn_s_setprio(0);
    // ---- step boundary: tile t+1 must land; ONE barrier per step ----
    if (t < 15) {
      asm volatile("s_waitcnt vmcnt(0)" ::: "memory");
      __builtin_amdgcn_sched_barrier(0);
    }
    __builtin_amdgcn_s_barrier();
  }

  if (z < 2) {
    const float sc = z == 0 ? QSC : 1.0f;
#pragma unroll
    for (int i = 0; i < 8; ++i)
#pragma unroll
      for (int j = 0; j < 4; ++j)
#pragma unroll
        for (int r = 0; r < 4; ++r) {
          float v = fmaxf(acc[i][j][r], 0.f) * sc;
          int m = m0 + wm * 128 + i * 16 + quad * 4 + r;
          int n = n0 + wn * 64 + j * 16 + l15;
          out[(size_t)m * 1024 + n] = f2bf(v);
        }
  } else {
    // acc = V^T tile: row = feature (m0+...), col = token (n0+...).
    // Repack through LDS [feat 256][tok-local 128], two token-halves,
    // then coalesced u16x8 stores to Vt[b*1024 + feat][token].
    const int bb = n0 >> 11, s0 = n0 & 2047;
#pragma unroll
    for (int half = 0; half < 2; ++half) {
      __syncthreads();
      if ((wn >> 1) == half) {
#pragma unroll
        for (int i = 0; i < 8; ++i)
#pragma unroll
          for (int j = 0; j < 4; ++j)
#pragma unroll
            for (int r = 0; r < 4; ++r) {
              const int row = wm * 128 + i * 16 + quad * 4 + r;
              const int col = (wn & 1) * 64 + j * 16 + l15;
              smem[row * 128 + col] = f2bf(fmaxf(acc[i][j][r], 0.f));
            }
      }
      __syncthreads();
#pragma unroll
      for (int i2 = 0; i2 < 8; ++i2) {
        const int c = i2 * 512 + tid;
        const int row = c >> 4, ch = c & 15;
        u16* dst = out + (size_t)(bb * 1024 + m0 + row) * 2048 + s0 +
                   half * 128 + ch * 8;
        *(u16x8*)dst = *(u16x8*)&smem[row * 128 + ch * 8];
      }
    }
  }
}

// ---------------------------------------------------------------------------
// Output GEMM: relu(ctx @ Wo), fp32 out — 256x128 tile, BK=64, 4 waves
// (2M x 2N, per-wave 128x64), same minimum-2-phase step as gemm_fwd.
// 96KB dbuf LDS, grid 32x8 = 256 blocks = exactly 1/CU, 16 steps.
// ---------------------------------------------------------------------------
__launch_bounds__(256, 2)
__global__ void gemm_out(const u16* __restrict__ A, const u16* __restrict__ Bt,
                         float* __restrict__ out) {
  __shared__ u16 smem[49152];  // 96KB: 2 bufs x (A 16384 u16 | B 8192 u16)
  const int tid = threadIdx.x;
  const int lane = tid & 63, l15 = lane & 15, quad = lane >> 4;
  const int wv = tid >> 6, wm = wv & 1, wn = wv >> 1;
  const int mblk = ((blockIdx.x & 7) << 2) | (blockIdx.x >> 3);
  const int m0 = mblk * 256;
  const int n0 = blockIdx.y * 128;

  // A: chunk c = i*256+tid (i 0..7): row=c&255, kc=c>>8.
  // B: chunk c = i*256+tid (i 0..3): row=c&127, kc=c>>7.
  const u16* gA[8];
#pragma unroll
  for (int i = 0; i < 8; ++i) {
    const int c = i * 256 + tid;
    gA[i] = A + (size_t)(m0 + (c & 255)) * 1024 + (c >> 8) * 8;
  }
  const u16* gB[4];
#pragma unroll
  for (int i = 0; i < 4; ++i) {
    const int c = i * 256 + tid;
    gB[i] = Bt + (size_t)(n0 + (c & 127)) * 1024 + (c >> 7) * 8;
  }

  const int offA = (quad * 256 + wm * 128 + l15) * 8;          // +8192 for kk1
  const int offB = 16384 + (quad * 128 + wn * 64 + l15) * 8;   // +4096 for kk1

  f32x4 acc[8][4] = {};

#pragma unroll
  for (int i = 0; i < 8; ++i) dma16(gA[i], &smem[i * 2048 + wv * 512]);
#pragma unroll
  for (int i = 0; i < 4; ++i) dma16(gB[i], &smem[16384 + i * 2048 + wv * 512]);
  asm volatile("s_waitcnt vmcnt(0)" ::: "memory");
  __builtin_amdgcn_sched_barrier(0);
  __builtin_amdgcn_s_barrier();

#pragma unroll 1
  for (int t = 0; t < 16; ++t) {
    const int bo = (t & 1) ? 24576 : 0;
    const int nbo = bo ^ 24576;
    bf16x8 a[4], b[4];
    // ---- kk=0: stage A(t+1) ----
    if (t < 15) {
#pragma unroll
      for (int i = 0; i < 8; ++i)
        dma16(gA[i] + (t + 1) * 64, &smem[nbo + i * 2048 + wv * 512]);
    }
#pragma unroll
    for (int j = 0; j < 4; ++j) b[j] = ld_frag(&smem[bo + offB + j * 128]);
#pragma unroll
    for (int i = 0; i < 4; ++i) a[i] = ld_frag(&smem[bo + offA + i * 128]);
    asm volatile("s_waitcnt lgkmcnt(0)" ::: "memory");
    __builtin_amdgcn_sched_barrier(0);
    __builtin_amdgcn_s_setprio(1);
#pragma unroll
    for (int i = 0; i < 4; ++i)
#pragma unroll
      for (int j = 0; j < 4; ++j)
        acc[i][j] = MFMA16(a[i], b[j], acc[i][j]);
    __builtin_amdgcn_s_setprio(0);
#pragma unroll
    for (int i = 0; i < 4; ++i)
      a[i] = ld_frag(&smem[bo + offA + (4 + i) * 128]);
    asm volatile("s_waitcnt lgkmcnt(0)" ::: "memory");
    __builtin_amdgcn_sched_barrier(0);
    __builtin_amdgcn_s_setprio(1);
#pragma unroll
    for (int i = 0; i < 4; ++i)
#pragma unroll
      for (int j = 0; j < 4; ++j)
        acc[4 + i][j] = MFMA16(a[i], b[j], acc[4 + i][j]);
    __builtin_amdgcn_s_setprio(0);
    // ---- kk=1: stage B(t+1) ----
    if (t < 15) {
#pragma unroll
      for (int i = 0; i < 4; ++i)
        dma16(gB[i] + (t + 1) * 64, &smem[nbo + 16384 + i * 2048 + wv * 512]);
    }
#pragma unroll
    for (int j = 0; j < 4; ++j)
      b[j] = ld_frag(&smem[bo + offB + 4096 + j * 128]);
#pragma unroll
    for (int i = 0; i < 4; ++i)
      a[i] = ld_frag(&smem[bo + offA + 8192 + i * 128]);
    asm volatile("s_waitcnt lgkmcnt(0)" ::: "memory");
    __builtin_amdgcn_sched_barrier(0);
    __builtin_amdgcn_s_setprio(1);
#pragma unroll
    for (int i = 0; i < 4; ++i)
#pragma unroll
      for (int j = 0; j < 4; ++j)
        acc[i][j] = MFMA16(a[i], b[j], acc[i][j]);
    __builtin_amdgcn_s_setprio(0);
#pragma unroll
    for (int i = 0; i < 4; ++i)
      a[i] = ld_frag(&smem[bo + offA + 8192 + (4 + i) * 128]);
    asm volatile("s_waitcnt lgkmcnt(0)" ::: "memory");
    __builtin_amdgcn_sched_barrier(0);
    __builtin_amdgcn_s_setprio(1);
#pragma unroll
    for (int i = 0; i < 4; ++i)
#pragma unroll
      for (int j = 0; j < 4; ++j)
        acc[4 + i][j] = MFMA16(a[i], b[j], acc[4 + i][j]);
    __builtin_amdgcn_s_setprio(0);
    if (t < 15) {
      asm volatile("s_waitcnt vmcnt(0)" ::: "memory");
      __builtin_amdgcn_sched_barrier(0);
    }
    __builtin_amdgcn_s_barrier();
  }

#pragma unroll
  for (int i = 0; i < 8; ++i)
#pragma unroll
    for (int j = 0; j < 4; ++j)
#pragma unroll
      for (int r = 0; r < 4; ++r) {
        int m = m0 + wm * 128 + i * 16 + quad * 4 + r;
        int n = n0 + wn * 64 + j * 16 + l15;
        out[(size_t)m * 1024 + n] = fmaxf(acc[i][j][r], 0.f);
      }
}

// ---------------------------------------------------------------------------
// Flash attention v9 — 64 q rows per wave (qh=4), 256 q per block.
// Grid (64,8) = 512 blocks = exactly 2/CU, both resident (64KB LDS)
// -> zero tail.  Same verified layouts as prior rounds.
// ---------------------------------------------------------------------------
__launch_bounds__(256, 2)
__global__ void attn(const u16* __restrict__ Q, const u16* __restrict__ K,
                     const u16* __restrict__ V, u16* __restrict__ ctx) {
  __shared__ u16 Ksm[2][4096];  // chunks [dc(8)][key(64)] x 8 u16 (8KB/buf)
  __shared__ u16 Vsm[2][4096];  // chunks [kc(8)][d(64)]  x 8 u16
  __shared__ u16 Psm[4][4096];  // per-wave chunks [kc(8)][q(64)] x 8 u16

  const int tid = threadIdx.x;
  const int lane = tid & 63, l15 = lane & 15, quad = lane >> 4;
  const int wv = tid >> 6;
  const int bh = blockIdx.x, b = bh >> 4, h = bh & 15;
  const int q0 = blockIdx.y * 256 + wv * 64;

  const u16* Kb = K + ((size_t)b * 2048) * 1024 + h * 64;
  const u16* Vb = V + (size_t)bh * 64 * 2048;
  u16* Pw = Psm[wv];

  const int ck0 = tid, ck1 = 256 + tid;
  const u16* kg0 = Kb + (size_t)(ck0 & 63) * 1024 + (ck0 >> 6) * 8;
  const u16* kg1 = Kb + (size_t)(ck1 & 63) * 1024 + (ck1 >> 6) * 8;
  const u16* vg0 = Vb + (size_t)(ck0 & 63) * 2048 + (ck0 >> 6) * 8;
  const u16* vg1 = Vb + (size_t)(ck1 & 63) * 2048 + (ck1 >> 6) * 8;

  // Q B-frags (pre-scaled by 0.125*log2e), resident all kernel (32 VGPR)
  bf16x8 aq[4][2];
#pragma unroll
  for (int qh = 0; qh < 4; ++qh)
#pragma unroll
    for (int kk = 0; kk < 2; ++kk)
      aq[qh][kk] = ld_frag(Q + (size_t)(b * 2048 + q0 + qh * 16 + l15) * 1024 +
                           h * 64 + kk * 32 + quad * 8);

  f32x4 o[4][4] = {};
  float ls[4] = {0.f, 0.f, 0.f, 0.f};

  dma16(kg0, &Ksm[0][ck0 * 8]);
  dma16(kg1, &Ksm[0][ck1 * 8]);
  dma16(vg0, &Vsm[0][ck0 * 8]);
  dma16(vg1, &Vsm[0][ck1 * 8]);

#pragma unroll 1
  for (int t = 0; t < 32; ++t) {
    const int cur = t & 1, nxt = cur ^ 1;
    __syncthreads();  // drains tile-t DMA (vmcnt) + prior tile's LDS reads (WAR)

    if (t + 1 < 32) {
      const int kadv = (t + 1) * 64;
      dma16(kg0 + (size_t)kadv * 1024, &Ksm[nxt][ck0 * 8]);
      dma16(kg1 + (size_t)kadv * 1024, &Ksm[nxt][ck1 * 8]);
      dma16(vg0 + kadv, &Vsm[nxt][ck0 * 8]);
      dma16(vg1 + kadv, &Vsm[nxt][ck1 * 8]);
    }

    bf16x8 kf[2][4];
#pragma unroll
    for (int kk = 0; kk < 2; ++kk)
#pragma unroll
      for (int jj = 0; jj < 4; ++jj)
        kf[kk][jj] = ld_frag(&Ksm[cur][((kk * 4 + quad) * 64 + jj * 16 + l15) * 8]);

    f32x4 st[4][4] = {};
    asm volatile("s_waitcnt lgkmcnt(0)" ::: "memory");
    __builtin_amdgcn_sched_barrier(0);
    __builtin_amdgcn_s_setprio(1);
#pragma unroll
    for (int kk = 0; kk < 2; ++kk)
#pragma unroll
      for (int jj = 0; jj < 4; ++jj)
#pragma unroll
        for (int qh = 0; qh < 4; ++qh)
          st[qh][jj] = MFMA16(kf[kk][jj], aq[qh][kk], st[qh][jj]);
    __builtin_amdgcn_s_setprio(0);

#pragma unroll
    for (int qh = 0; qh < 4; ++qh)
#pragma unroll
      for (int jj = 0; jj < 4; ++jj) {
        float p0 = EXP2(st[qh][jj][0]), p1 = EXP2(st[qh][jj][1]);
        float p2 = EXP2(st[qh][jj][2]), p3 = EXP2(st[qh][jj][3]);
        ls[qh] += (p0 + p1) + (p2 + p3);
        u16x4 pk;
        pk[0] = cvt_bf(p0); pk[1] = cvt_bf(p1);
        pk[2] = cvt_bf(p2); pk[3] = cvt_bf(p3);
        const int kc = jj * 2 + (quad >> 1);
        *(u16x4*)&Pw[(kc * 64 + qh * 16 + l15) * 8 + (quad & 1) * 4] = pk;
      }

#pragma unroll
    for (int kk = 0; kk < 2; ++kk) {
      bf16x8 pa[4];
#pragma unroll
      for (int qh = 0; qh < 4; ++qh)
        pa[qh] = ld_frag(&Pw[((kk * 4 + quad) * 64 + qh * 16 + l15) * 8]);
      asm volatile("s_waitcnt lgkmcnt(0)" ::: "memory");
      __builtin_amdgcn_sched_barrier(0);
      __builtin_amdgcn_s_setprio(1);
#pragma unroll
      for (int j = 0; j < 4; ++j) {
        bf16x8 vb = ld_frag(&Vsm[cur][((kk * 4 + quad) * 64 + j * 16 + l15) * 8]);
#pragma unroll
        for (int qh = 0; qh < 4; ++qh)
          o[qh][j] = MFMA16(vb, pa[qh], o[qh][j]);
      }
      __builtin_amdgcn_s_setprio(0);
    }
  }

  float inv[4];
#pragma unroll
  for (int qh = 0; qh < 4; ++qh) {
    ls[qh] += __shfl_xor(ls[qh], 16, 64);
    ls[qh] += __shfl_xor(ls[qh], 32, 64);
    inv[qh] = 1.f / ls[qh];
  }

#pragma unroll
  for (int qh = 0; qh < 4; ++qh) {
    const int tok = b * 2048 + q0 + qh * 16 + l15;
#pragma unroll
    for (int j = 0; j < 4; ++j) {
      u16x4 pk;
#pragma unroll
      for (int r = 0; r < 4; ++r) pk[r] = cvt_bf(o[qh][j][r] * inv[qh]);
      *(u16x4*)&ctx[(size_t)tok * 1024 + h * 64 + j * 16 + quad * 4] = pk;
    }
  }
}

// ---------------------------------------------------------------------------
extern "C" void kernel_launch(void* const* d_in, const int* in_sizes, int n_in,
                              void* d_out, int out_size, void* d_ws, size_t ws_size,
                              hipStream_t stream) {
  const float* query = (const float*)d_in[0];
  const float* key   = (const float*)d_in[1];
  const float* value = (const float*)d_in[2];
  const float* Wq = (const float*)d_in[3];
  const float* Wk = (const float*)d_in[4];
  const float* Wv = (const float*)d_in[5];
  const float* Wo = (const float*)d_in[6];
  float* outp = (float*)d_out;

  // ws (u16 units): Wt 4Mi | Awq 8Mi | Qw 8Mi | Kw 8Mi | Vt 8Mi = 72 MB.
  // Awk/Awv live in d_out (32 MB, consumed before gemm_out overwrites it);
  // ctx aliases Awq (consumed by gemm_fwd before attn writes it).
  u16* Wt  = (u16*)d_ws;
  u16* Awq = Wt + ((size_t)4 << 20);
  u16* Qw  = Awq + ((size_t)8 << 20);
  u16* Kw  = Qw + ((size_t)8 << 20);
  u16* Vt  = Kw + ((size_t)8 << 20);
  u16* Awk = (u16*)d_out;
  u16* Awv = Awk + ((size_t)8 << 20);
  u16* Cw  = Awq;

  prep_w<<<dim3(16, 16, 4), 256, 0, stream>>>(Wq, Wk, Wv, Wo, Wt);
  prep_a<<<dim3(1024, 1, 3), 256, 0, stream>>>(query, key, value, Awq, Awk, Awv);
  gemm_fwd<<<dim3(32, 4, 3), 512, 0, stream>>>(Awq, Awk, Awv, Wt, Qw, Kw, Vt);
  attn<<<dim3(64, 8), 256, 0, stream>>>(Qw, Kw, Vt, Cw);
  gemm_out<<<dim3(32, 8), 256, 0, stream>>>(Cw, Wt + ((size_t)3 << 20), outp);
}

// Round 8
// 360.521 us; speedup vs baseline: 1.0206x; 1.0116x over previous
//
#include <hip/hip_runtime.h>

typedef unsigned short u16;
typedef __bf16 bf16x8 __attribute__((ext_vector_type(8)));
typedef float f32x4 __attribute__((ext_vector_type(4)));
typedef u16 u16x8 __attribute__((ext_vector_type(8)));
typedef u16 u16x4 __attribute__((ext_vector_type(4)));

#define MFMA16(a, b, c) __builtin_amdgcn_mfma_f32_16x16x32_bf16(a, b, c, 0, 0, 0)

static constexpr float QSC = 0.18033688011112042f;  // 0.125 * log2(e)

__device__ inline u16 f2bf(float f) {
  union { float f; unsigned u; } x; x.f = f;
  unsigned r = x.u + 0x7FFF + ((x.u >> 16) & 1);  // RNE
  return (u16)(r >> 16);
}
__device__ inline u16 cvt_bf(float f) {  // native, pairs into v_cvt_pk_bf16_f32
  __bf16 h = (__bf16)f; return __builtin_bit_cast(u16, h);
}
__device__ inline bf16x8 ld_frag(const u16* p) {
  return __builtin_bit_cast(bf16x8, *(const u16x8*)p);
}
__device__ inline void dma16(const u16* g, u16* l) {
  __builtin_amdgcn_global_load_lds(
      (const __attribute__((address_space(1))) unsigned*)g,
      (__attribute__((address_space(3))) unsigned*)l, 16, 0, 0);
}

#if __has_builtin(__builtin_amdgcn_exp2f)
#define EXP2(x) __builtin_amdgcn_exp2f(x)
#else
#define EXP2(x) exp2f(x)
#endif

// ---------------------------------------------------------------------------
// Weight transpose-convert: W[k][n] fp32 -> Wt[n][k] bf16. z selects weight.
// ---------------------------------------------------------------------------
__launch_bounds__(256)
__global__ void prep_w(const float* __restrict__ Wq, const float* __restrict__ Wk,
                       const float* __restrict__ Wv, const float* __restrict__ Wo,
                       u16* __restrict__ Wt) {
  __shared__ u16 T[64 * 72];
  const int z = blockIdx.z;
  const float* W = z == 0 ? Wq : z == 1 ? Wk : z == 2 ? Wv : Wo;
  u16* D = Wt + ((size_t)z << 20);
  const int k0 = blockIdx.y * 64, c0 = blockIdx.x * 64;
  const int tid = threadIdx.x;
  const int kr = tid >> 2, cs = (tid & 3) * 16;
  const float* src = W + (size_t)(k0 + kr) * 1024 + c0 + cs;
  float f[16];
#pragma unroll
  for (int i = 0; i < 4; ++i) *(float4*)&f[i * 4] = ((const float4*)src)[i];
#pragma unroll
  for (int i = 0; i < 16; ++i) T[(cs + i) * 72 + kr] = cvt_bf(f[i]);
  __syncthreads();
  const int nn = tid >> 2, ks = (tid & 3) * 16;
  u16* dst = D + (size_t)(c0 + nn) * 1024 + k0 + ks;
  *(u16x8*)dst = *(u16x8*)&T[nn * 72 + ks];
  *(u16x8*)(dst + 8) = *(u16x8*)&T[nn * 72 + ks + 8];
}

// ---------------------------------------------------------------------------
// Input convert: fp32 -> bf16 row-major. z selects tensor (8Mi elems each).
// ---------------------------------------------------------------------------
__launch_bounds__(256)
__global__ void prep_a(const float* __restrict__ q, const float* __restrict__ k,
                       const float* __restrict__ v, u16* __restrict__ dq,
                       u16* __restrict__ dk, u16* __restrict__ dv) {
  const int z = blockIdx.z;
  const float* s = z == 0 ? q : z == 1 ? k : v;
  u16* d = z == 0 ? dq : z == 1 ? dk : dv;
  for (size_t i = blockIdx.x * 256 + threadIdx.x; i < (size_t)1048576; i += 262144) {
    const float* g = s + i * 8;
    float4 f0 = *(const float4*)g, f1 = *(const float4*)(g + 4);
    u16x8 h;
    h[0] = cvt_bf(f0.x); h[1] = cvt_bf(f0.y); h[2] = cvt_bf(f0.z); h[3] = cvt_bf(f0.w);
    h[4] = cvt_bf(f1.x); h[5] = cvt_bf(f1.y); h[6] = cvt_bf(f1.z); h[7] = cvt_bf(f1.w);
    *(u16x8*)(d + i * 8) = h;
  }
}

// ---------------------------------------------------------------------------
// QKV GEMM — 256x256 tile, BK=64, 8 waves, FINE-GRAINED 4-phase schedule
// (m201-style): per K-tile t (buffers ping-pong on t&1):
//   P1: read b(kk0)x4 + a(mi0-3,kk0)x4 | stage A-Khalf0(t+1) | bar | lgkm0 |
//       16 MFMA (mi0-3 x nj0-3, kk0) | vmcnt(2) | bar
//   P2: read b(kk1)x4 + a(mi0-3,kk1)x4 | stage B-Khalf0(t+1) | ... 16 MFMA | bar
//   P3: read a(mi4-7,kk0)x4 (b kk0 reused from regs) | stage A-Khalf1(t+1)
//       | ... 16 MFMA | bar
//   P4: read a(mi4-7,kk1)x4 | stage B-Khalf1(t+1) | ... 16 MFMA | vmcnt(4) | bar
// Counted-vmcnt invariants (2 loads per half-stage, per thread):
//   - vm(4)@P4(t): oldest 4 of the 8 outstanding done -> A-Kh0(t+1),B-Kh0(t+1)
//     landed before P1(t+1) reads them; P3,P4 stages stay in flight.
//   - vm(2)@P1(t): A-Kh1(t),B-Kh1(t) (staged P3,P4 of t-1, older than P1(t)'s
//     stage) landed before P2(t); never drains to 0 mid-loop (0 only at t=15).
//   - WAR: each staged region's last ds_read drained (lgkm0+barrier) >=2
//     barriers before the stage issue (dbuf: stage targets the other buffer).
// Data layout IDENTICAL bytes to the verified BK=64 kernel (chunked linear,
// conflict-free): A-tile 2048 chunks [kc 0-7][row 0-255], K-half = kc0-3.
// LDS u16 idx: A0@0 B0@16384 A1@32768 B1@49152 (128KB).
// z=0: Q=relu*QSC; z=1: K; z=2: operand-swapped -> acc=V^T, repack to Vt.
// ---------------------------------------------------------------------------
__launch_bounds__(512, 2)
__global__ void gemm_fwd(const u16* __restrict__ Aq, const u16* __restrict__ Ak,
                         const u16* __restrict__ Av, const u16* __restrict__ Wt,
                         u16* __restrict__ Qw, u16* __restrict__ Kw,
                         u16* __restrict__ Vw) {
  __shared__ u16 smem[65536];  // 128KB
  const int z = blockIdx.z;
  const u16* A = z == 0 ? Aq : z == 1 ? Ak : Av;
  const u16* Bt = Wt + ((size_t)z << 20);
  u16* out = z == 0 ? Qw : z == 1 ? Kw : Vw;
  const u16* Aop = (z == 2) ? Bt : A;
  const u16* Bop = (z == 2) ? A : Bt;

  const int tid = threadIdx.x;
  const int lane = tid & 63, l15 = lane & 15, quad = lane >> 4;
  const int wv = tid >> 6, wm = wv & 1, wn = wv >> 1;  // 2M x 4N wave grid
  const int mblk = ((blockIdx.x & 7) << 2) | (blockIdx.x >> 3);
  const int m0 = (z == 2) ? blockIdx.y * 256 : mblk * 256;
  const int n0 = (z == 2) ? mblk * 256 : blockIdx.y * 256;

  // Staging: per half, 2 dma/thread. chunk-in-half c = i*512+tid:
  // row = c&255, kc' = c>>8 (0..3); global col = t*64 + h*32 + kc'*8.
  const u16* gA[2];
  const u16* gB[2];
#pragma unroll
  for (int i = 0; i < 2; ++i) {
    const int c = i * 512 + tid;
    gA[i] = Aop + (size_t)(m0 + (c & 255)) * 1024 + (c >> 8) * 8;
    gB[i] = Bop + (size_t)(n0 + (c & 255)) * 1024 + (c >> 8) * 8;
  }
  const int ub0 = (wv * 64) * 8, ub1 = (512 + wv * 64) * 8;  // wave-uniform

  // Frag offsets (u16): chunk = kk*1024 + quad*256 + row; idx = chunk*8.
  const int offA = (quad * 256 + wm * 128 + l15) * 8;  // + mi*128, +8192 kk1
  const int offB = (quad * 256 + wn * 64 + l15) * 8;   // + nj*128, +8192 kk1

  f32x4 acc[8][4] = {};

  // Prologue: stage tile 0 (4 halves) -> buf0; full drain; barrier.
#pragma unroll
  for (int h = 0; h < 2; ++h) {
    dma16(gA[0] + h * 32, &smem[h * 8192 + ub0]);
    dma16(gA[1] + h * 32, &smem[h * 8192 + ub1]);
    dma16(gB[0] + h * 32, &smem[16384 + h * 8192 + ub0]);
    dma16(gB[1] + h * 32, &smem[16384 + h * 8192 + ub1]);
  }
  asm volatile("s_waitcnt vmcnt(0)" ::: "memory");
  __builtin_amdgcn_sched_barrier(0);
  __builtin_amdgcn_s_barrier();

#pragma unroll 1
  for (int t = 0; t < 16; ++t) {
    const int pb = (t & 1) * 32768;
    const int nb = 32768 - pb;
    const u16* aB = smem + pb;
    const u16* bB = smem + pb + 16384;
    u16* nA = smem + nb;
    u16* nBf = smem + nb + 16384;
    const int adv = (t + 1) * 64;
    bf16x8 bk0[4], bk1[4], a[4];

    // ---------------- P1: kk0, mi0-3 ----------------
#pragma unroll
    for (int j = 0; j < 4; ++j) bk0[j] = ld_frag(bB + offB + j * 128);
#pragma unroll
    for (int i = 0; i < 4; ++i) a[i] = ld_frag(aB + offA + i * 128);
    if (t < 15) {
      dma16(gA[0] + adv, &nA[ub0]);
      dma16(gA[1] + adv, &nA[ub1]);
    }
    __builtin_amdgcn_s_barrier();
    asm volatile("s_waitcnt lgkmcnt(0)" ::: "memory");
    __builtin_amdgcn_sched_barrier(0);
    __builtin_amdgcn_s_setprio(1);
#pragma unroll
    for (int i = 0; i < 4; ++i)
#pragma unroll
      for (int j = 0; j < 4; ++j)
        acc[i][j] = MFMA16(a[i], bk0[j], acc[i][j]);
    __builtin_amdgcn_s_setprio(0);
    if (t < 15)
      asm volatile("s_waitcnt vmcnt(2)" ::: "memory");
    else
      asm volatile("s_waitcnt vmcnt(0)" ::: "memory");
    __builtin_amdgcn_sched_barrier(0);
    __builtin_amdgcn_s_barrier();

    // ---------------- P2: kk1, mi0-3 ----------------
#pragma unroll
    for (int j = 0; j < 4; ++j) bk1[j] = ld_frag(bB + offB + 8192 + j * 128);
#pragma unroll
    for (int i = 0; i < 4; ++i) a[i] = ld_frag(aB + offA + 8192 + i * 128);
    if (t < 15) {
      dma16(gB[0] + adv, &nBf[ub0]);
      dma16(gB[1] + adv, &nBf[ub1]);
    }
    __builtin_amdgcn_s_barrier();
    asm volatile("s_waitcnt lgkmcnt(0)" ::: "memory");
    __builtin_amdgcn_sched_barrier(0);
    __builtin_amdgcn_s_setprio(1);
#pragma unroll
    for (int i = 0; i < 4; ++i)
#pragma unroll
      for (int j = 0; j < 4; ++j)
        acc[i][j] = MFMA16(a[i], bk1[j], acc[i][j]);
    __builtin_amdgcn_s_setprio(0);
    __builtin_amdgcn_s_barrier();

    // ---------------- P3: kk0, mi4-7 (b kk0 reused) ----------------
#pragma unroll
    for (int i = 0; i < 4; ++i) a[i] = ld_frag(aB + offA + (4 + i) * 128);
    if (t < 15) {
      dma16(gA[0] + adv + 32, &nA[8192 + ub0]);
      dma16(gA[1] + adv + 32, &nA[8192 + ub1]);
    }
    __builtin_amdgcn_s_barrier();
    asm volatile("s_waitcnt lgkmcnt(0)" ::: "memory");
    __builtin_amdgcn_sched_barrier(0);
    __builtin_amdgcn_s_setprio(1);
#pragma unroll
    for (int i = 0; i < 4; ++i)
#pragma unroll
      for (int j = 0; j < 4; ++j)
        acc[4 + i][j] = MFMA16(a[i], bk0[j], acc[4 + i][j]);
    __builtin_amdgcn_s_setprio(0);
    __builtin_amdgcn_s_barrier();

    // ---------------- P4: kk1, mi4-7 (b kk1 reused) ----------------
#pragma unroll
    for (int i = 0; i < 4; ++i) a[i] = ld_frag(aB + offA + 8192 + (4 + i) * 128);
    if (t < 15) {
      dma16(gB[0] + adv + 32, &nBf[8192 + ub0]);
      dma16(gB[1] + adv + 32, &nBf[8192 + ub1]);
    }
    __builtin_amdgcn_s_barrier();
    asm volatile("s_waitcnt lgkmcnt(0)" ::: "memory");
    __builtin_amdgcn_sched_barrier(0);
    __builtin_amdgcn_s_setprio(1);
#pragma unroll
    for (int i = 0; i < 4; ++i)
#pragma unroll
      for (int j = 0; j < 4; ++j)
        acc[4 + i][j] = MFMA16(a[i], bk1[j], acc[4 + i][j]);
    __builtin_amdgcn_s_setprio(0);
    if (t < 15) {
      asm volatile("s_waitcnt vmcnt(4)" ::: "memory");
      __builtin_amdgcn_sched_barrier(0);
    }
    __builtin_amdgcn_s_barrier();
  }

  if (z < 2) {
    const float sc = z == 0 ? QSC : 1.0f;
#pragma unroll
    for (int i = 0; i < 8; ++i)
#pragma unroll
      for (int j = 0; j < 4; ++j)
#pragma unroll
        for (int r = 0; r < 4; ++r) {
          float v = fmaxf(acc[i][j][r], 0.f) * sc;
          int m = m0 + wm * 128 + i * 16 + quad * 4 + r;
          int n = n0 + wn * 64 + j * 16 + l15;
          out[(size_t)m * 1024 + n] = f2bf(v);
        }
  } else {
    // acc = V^T tile: row = feature (m0+...), col = token (n0+...).
    // Repack through LDS [feat 256][tok-local 128], two token-halves,
    // then coalesced u16x8 stores to Vt[b*1024 + feat][token].
    const int bb = n0 >> 11, s0 = n0 & 2047;
#pragma unroll
    for (int half = 0; half < 2; ++half) {
      __syncthreads();
      if ((wn >> 1) == half) {
#pragma unroll
        for (int i = 0; i < 8; ++i)
#pragma unroll
          for (int j = 0; j < 4; ++j)
#pragma unroll
            for (int r = 0; r < 4; ++r) {
              const int row = wm * 128 + i * 16 + quad * 4 + r;
              const int col = (wn & 1) * 64 + j * 16 + l15;
              smem[row * 128 + col] = f2bf(fmaxf(acc[i][j][r], 0.f));
            }
      }
      __syncthreads();
#pragma unroll
      for (int i2 = 0; i2 < 8; ++i2) {
        const int c = i2 * 512 + tid;
        const int row = c >> 4, ch = c & 15;
        u16* dst = out + (size_t)(bb * 1024 + m0 + row) * 2048 + s0 +
                   half * 128 + ch * 8;
        *(u16x8*)dst = *(u16x8*)&smem[row * 128 + ch * 8];
      }
    }
  }
}

// ---------------------------------------------------------------------------
// Output GEMM: relu(ctx @ Wo), fp32 out — 256x128 tile, BK=64, 4 waves
// (2M x 2N, per-wave 128x64), minimum-2-phase step.
// 96KB dbuf LDS, grid 32x8 = 256 blocks = exactly 1/CU, 16 steps.
// ---------------------------------------------------------------------------
__launch_bounds__(256, 2)
__global__ void gemm_out(const u16* __restrict__ A, const u16* __restrict__ Bt,
                         float* __restrict__ out) {
  __shared__ u16 smem[49152];  // 96KB: 2 bufs x (A 16384 u16 | B 8192 u16)
  const int tid = threadIdx.x;
  const int lane = tid & 63, l15 = lane & 15, quad = lane >> 4;
  const int wv = tid >> 6, wm = wv & 1, wn = wv >> 1;
  const int mblk = ((blockIdx.x & 7) << 2) | (blockIdx.x >> 3);
  const int m0 = mblk * 256;
  const int n0 = blockIdx.y * 128;

  const u16* gA[8];
#pragma unroll
  for (int i = 0; i < 8; ++i) {
    const int c = i * 256 + tid;
    gA[i] = A + (size_t)(m0 + (c & 255)) * 1024 + (c >> 8) * 8;
  }
  const u16* gB[4];
#pragma unroll
  for (int i = 0; i < 4; ++i) {
    const int c = i * 256 + tid;
    gB[i] = Bt + (size_t)(n0 + (c & 127)) * 1024 + (c >> 7) * 8;
  }

  const int offA = (quad * 256 + wm * 128 + l15) * 8;          // +8192 for kk1
  const int offB = 16384 + (quad * 128 + wn * 64 + l15) * 8;   // +4096 for kk1

  f32x4 acc[8][4] = {};

#pragma unroll
  for (int i = 0; i < 8; ++i) dma16(gA[i], &smem[i * 2048 + wv * 512]);
#pragma unroll
  for (int i = 0; i < 4; ++i) dma16(gB[i], &smem[16384 + i * 2048 + wv * 512]);
  asm volatile("s_waitcnt vmcnt(0)" ::: "memory");
  __builtin_amdgcn_sched_barrier(0);
  __builtin_amdgcn_s_barrier();

#pragma unroll 1
  for (int t = 0; t < 16; ++t) {
    const int bo = (t & 1) ? 24576 : 0;
    const int nbo = bo ^ 24576;
    bf16x8 a[4], b[4];
    if (t < 15) {
#pragma unroll
      for (int i = 0; i < 8; ++i)
        dma16(gA[i] + (t + 1) * 64, &smem[nbo + i * 2048 + wv * 512]);
    }
#pragma unroll
    for (int j = 0; j < 4; ++j) b[j] = ld_frag(&smem[bo + offB + j * 128]);
#pragma unroll
    for (int i = 0; i < 4; ++i) a[i] = ld_frag(&smem[bo + offA + i * 128]);
    asm volatile("s_waitcnt lgkmcnt(0)" ::: "memory");
    __builtin_amdgcn_sched_barrier(0);
    __builtin_amdgcn_s_setprio(1);
#pragma unroll
    for (int i = 0; i < 4; ++i)
#pragma unroll
      for (int j = 0; j < 4; ++j)
        acc[i][j] = MFMA16(a[i], b[j], acc[i][j]);
    __builtin_amdgcn_s_setprio(0);
#pragma unroll
    for (int i = 0; i < 4; ++i)
      a[i] = ld_frag(&smem[bo + offA + (4 + i) * 128]);
    asm volatile("s_waitcnt lgkmcnt(0)" ::: "memory");
    __builtin_amdgcn_sched_barrier(0);
    __builtin_amdgcn_s_setprio(1);
#pragma unroll
    for (int i = 0; i < 4; ++i)
#pragma unroll
      for (int j = 0; j < 4; ++j)
        acc[4 + i][j] = MFMA16(a[i], b[j], acc[4 + i][j]);
    __builtin_amdgcn_s_setprio(0);
    if (t < 15) {
#pragma unroll
      for (int i = 0; i < 4; ++i)
        dma16(gB[i] + (t + 1) * 64, &smem[nbo + 16384 + i * 2048 + wv * 512]);
    }
#pragma unroll
    for (int j = 0; j < 4; ++j)
      b[j] = ld_frag(&smem[bo + offB + 4096 + j * 128]);
#pragma unroll
    for (int i = 0; i < 4; ++i)
      a[i] = ld_frag(&smem[bo + offA + 8192 + i * 128]);
    asm volatile("s_waitcnt lgkmcnt(0)" ::: "memory");
    __builtin_amdgcn_sched_barrier(0);
    __builtin_amdgcn_s_setprio(1);
#pragma unroll
    for (int i = 0; i < 4; ++i)
#pragma unroll
      for (int j = 0; j < 4; ++j)
        acc[i][j] = MFMA16(a[i], b[j], acc[i][j]);
    __builtin_amdgcn_s_setprio(0);
#pragma unroll
    for (int i = 0; i < 4; ++i)
      a[i] = ld_frag(&smem[bo + offA + 8192 + (4 + i) * 128]);
    asm volatile("s_waitcnt lgkmcnt(0)" ::: "memory");
    __builtin_amdgcn_sched_barrier(0);
    __builtin_amdgcn_s_setprio(1);
#pragma unroll
    for (int i = 0; i < 4; ++i)
#pragma unroll
      for (int j = 0; j < 4; ++j)
        acc[4 + i][j] = MFMA16(a[i], b[j], acc[4 + i][j]);
    __builtin_amdgcn_s_setprio(0);
    if (t < 15) {
      asm volatile("s_waitcnt vmcnt(0)" ::: "memory");
      __builtin_amdgcn_sched_barrier(0);
    }
    __builtin_amdgcn_s_barrier();
  }

#pragma unroll
  for (int i = 0; i < 8; ++i)
#pragma unroll
    for (int j = 0; j < 4; ++j)
#pragma unroll
      for (int r = 0; r < 4; ++r) {
        int m = m0 + wm * 128 + i * 16 + quad * 4 + r;
        int n = n0 + wn * 64 + j * 16 + l15;
        out[(size_t)m * 1024 + n] = fmaxf(acc[i][j][r], 0.f);
      }
}

// ---------------------------------------------------------------------------
// Flash attention v9 — 64 q rows per wave (qh=4), 256 q per block.
// Grid (64,8) = 512 blocks = exactly 2/CU, both resident (64KB LDS)
// -> zero tail.  Same verified layouts as prior rounds.
// ---------------------------------------------------------------------------
__launch_bounds__(256, 2)
__global__ void attn(const u16* __restrict__ Q, const u16* __restrict__ K,
                     const u16* __restrict__ V, u16* __restrict__ ctx) {
  __shared__ u16 Ksm[2][4096];  // chunks [dc(8)][key(64)] x 8 u16 (8KB/buf)
  __shared__ u16 Vsm[2][4096];  // chunks [kc(8)][d(64)]  x 8 u16
  __shared__ u16 Psm[4][4096];  // per-wave chunks [kc(8)][q(64)] x 8 u16

  const int tid = threadIdx.x;
  const int lane = tid & 63, l15 = lane & 15, quad = lane >> 4;
  const int wv = tid >> 6;
  const int bh = blockIdx.x, b = bh >> 4, h = bh & 15;
  const int q0 = blockIdx.y * 256 + wv * 64;

  const u16* Kb = K + ((size_t)b * 2048) * 1024 + h * 64;
  const u16* Vb = V + (size_t)bh * 64 * 2048;
  u16* Pw = Psm[wv];

  const int ck0 = tid, ck1 = 256 + tid;
  const u16* kg0 = Kb + (size_t)(ck0 & 63) * 1024 + (ck0 >> 6) * 8;
  const u16* kg1 = Kb + (size_t)(ck1 & 63) * 1024 + (ck1 >> 6) * 8;
  const u16* vg0 = Vb + (size_t)(ck0 & 63) * 2048 + (ck0 >> 6) * 8;
  const u16* vg1 = Vb + (size_t)(ck1 & 63) * 2048 + (ck1 >> 6) * 8;

  // Q B-frags (pre-scaled by 0.125*log2e), resident all kernel (32 VGPR)
  bf16x8 aq[4][2];
#pragma unroll
  for (int qh = 0; qh < 4; ++qh)
#pragma unroll
    for (int kk = 0; kk < 2; ++kk)
      aq[qh][kk] = ld_frag(Q + (size_t)(b * 2048 + q0 + qh * 16 + l15) * 1024 +
                           h * 64 + kk * 32 + quad * 8);

  f32x4 o[4][4] = {};
  float ls[4] = {0.f, 0.f, 0.f, 0.f};

  dma16(kg0, &Ksm[0][ck0 * 8]);
  dma16(kg1, &Ksm[0][ck1 * 8]);
  dma16(vg0, &Vsm[0][ck0 * 8]);
  dma16(vg1, &Vsm[0][ck1 * 8]);

#pragma unroll 1
  for (int t = 0; t < 32; ++t) {
    const int cur = t & 1, nxt = cur ^ 1;
    __syncthreads();  // drains tile-t DMA (vmcnt) + prior tile's LDS reads (WAR)

    if (t + 1 < 32) {
      const int kadv = (t + 1) * 64;
      dma16(kg0 + (size_t)kadv * 1024, &Ksm[nxt][ck0 * 8]);
      dma16(kg1 + (size_t)kadv * 1024, &Ksm[nxt][ck1 * 8]);
      dma16(vg0 + kadv, &Vsm[nxt][ck0 * 8]);
      dma16(vg1 + kadv, &Vsm[nxt][ck1 * 8]);
    }

    bf16x8 kf[2][4];
#pragma unroll
    for (int kk = 0; kk < 2; ++kk)
#pragma unroll
      for (int jj = 0; jj < 4; ++jj)
        kf[kk][jj] = ld_frag(&Ksm[cur][((kk * 4 + quad) * 64 + jj * 16 + l15) * 8]);

    f32x4 st[4][4] = {};
    asm volatile("s_waitcnt lgkmcnt(0)" ::: "memory");
    __builtin_amdgcn_sched_barrier(0);
    __builtin_amdgcn_s_setprio(1);
#pragma unroll
    for (int kk = 0; kk < 2; ++kk)
#pragma unroll
      for (int jj = 0; jj < 4; ++jj)
#pragma unroll
        for (int qh = 0; qh < 4; ++qh)
          st[qh][jj] = MFMA16(kf[kk][jj], aq[qh][kk], st[qh][jj]);
    __builtin_amdgcn_s_setprio(0);

#pragma unroll
    for (int qh = 0; qh < 4; ++qh)
#pragma unroll
      for (int jj = 0; jj < 4; ++jj) {
        float p0 = EXP2(st[qh][jj][0]), p1 = EXP2(st[qh][jj][1]);
        float p2 = EXP2(st[qh][jj][2]), p3 = EXP2(st[qh][jj][3]);
        ls[qh] += (p0 + p1) + (p2 + p3);
        u16x4 pk;
        pk[0] = cvt_bf(p0); pk[1] = cvt_bf(p1);
        pk[2] = cvt_bf(p2); pk[3] = cvt_bf(p3);
        const int kc = jj * 2 + (quad >> 1);
        *(u16x4*)&Pw[(kc * 64 + qh * 16 + l15) * 8 + (quad & 1) * 4] = pk;
      }

#pragma unroll
    for (int kk = 0; kk < 2; ++kk) {
      bf16x8 pa[4];
#pragma unroll
      for (int qh = 0; qh < 4; ++qh)
        pa[qh] = ld_frag(&Pw[((kk * 4 + quad) * 64 + qh * 16 + l15) * 8]);
      asm volatile("s_waitcnt lgkmcnt(0)" ::: "memory");
      __builtin_amdgcn_sched_barrier(0);
      __builtin_amdgcn_s_setprio(1);
#pragma unroll
      for (int j = 0; j < 4; ++j) {
        bf16x8 vb = ld_frag(&Vsm[cur][((kk * 4 + quad) * 64 + j * 16 + l15) * 8]);
#pragma unroll
        for (int qh = 0; qh < 4; ++qh)
          o[qh][j] = MFMA16(vb, pa[qh], o[qh][j]);
      }
      __builtin_amdgcn_s_setprio(0);
    }
  }

  float inv[4];
#pragma unroll
  for (int qh = 0; qh < 4; ++qh) {
    ls[qh] += __shfl_xor(ls[qh], 16, 64);
    ls[qh] += __shfl_xor(ls[qh], 32, 64);
    inv[qh] = 1.f / ls[qh];
  }

#pragma unroll
  for (int qh = 0; qh < 4; ++qh) {
    const int tok = b * 2048 + q0 + qh * 16 + l15;
#pragma unroll
    for (int j = 0; j < 4; ++j) {
      u16x4 pk;
#pragma unroll
      for (int r = 0; r < 4; ++r) pk[r] = cvt_bf(o[qh][j][r] * inv[qh]);
      *(u16x4*)&ctx[(size_t)tok * 1024 + h * 64 + j * 16 + quad * 4] = pk;
    }
  }
}

// ---------------------------------------------------------------------------
extern "C" void kernel_launch(void* const* d_in, const int* in_sizes, int n_in,
                              void* d_out, int out_size, void* d_ws, size_t ws_size,
                              hipStream_t stream) {
  const float* query = (const float*)d_in[0];
  const float* key   = (const float*)d_in[1];
  const float* value = (const float*)d_in[2];
  const float* Wq = (const float*)d_in[3];
  const float* Wk = (const float*)d_in[4];
  const float* Wv = (const float*)d_in[5];
  const float* Wo = (const float*)d_in[6];
  float* outp = (float*)d_out;

  // ws (u16 units): Wt 4Mi | Awq 8Mi | Qw 8Mi | Kw 8Mi | Vt 8Mi = 72 MB.
  // Awk/Awv live in d_out (32 MB, consumed before gemm_out overwrites it);
  // ctx aliases Awq (consumed by gemm_fwd before attn writes it).
  u16* Wt  = (u16*)d_ws;
  u16* Awq = Wt + ((size_t)4 << 20);
  u16* Qw  = Awq + ((size_t)8 << 20);
  u16* Kw  = Qw + ((size_t)8 << 20);
  u16* Vt  = Kw + ((size_t)8 << 20);
  u16* Awk = (u16*)d_out;
  u16* Awv = Awk + ((size_t)8 << 20);
  u16* Cw  = Awq;

  prep_w<<<dim3(16, 16, 4), 256, 0, stream>>>(Wq, Wk, Wv, Wo, Wt);
  prep_a<<<dim3(1024, 1, 3), 256, 0, stream>>>(query, key, value, Awq, Awk, Awv);
  gemm_fwd<<<dim3(32, 4, 3), 512, 0, stream>>>(Awq, Awk, Awv, Wt, Qw, Kw, Vt);
  attn<<<dim3(64, 8), 256, 0, stream>>>(Qw, Kw, Vt, Cw);
  gemm_out<<<dim3(32, 8), 256, 0, stream>>>(Cw, Wt + ((size_t)3 << 20), outp);
}

// Round 9
// 350.800 us; speedup vs baseline: 1.0489x; 1.0277x over previous
//
#include <hip/hip_runtime.h>

typedef unsigned short u16;
typedef __bf16 bf16x8 __attribute__((ext_vector_type(8)));
typedef float f32x4 __attribute__((ext_vector_type(4)));
typedef u16 u16x8 __attribute__((ext_vector_type(8)));
typedef u16 u16x4 __attribute__((ext_vector_type(4)));

#define MFMA16(a, b, c) __builtin_amdgcn_mfma_f32_16x16x32_bf16(a, b, c, 0, 0, 0)

static constexpr float QSC = 0.18033688011112042f;  // 0.125 * log2(e)

__device__ inline u16 f2bf(float f) {
  union { float f; unsigned u; } x; x.f = f;
  unsigned r = x.u + 0x7FFF + ((x.u >> 16) & 1);  // RNE
  return (u16)(r >> 16);
}
__device__ inline u16 cvt_bf(float f) {  // native, pairs into v_cvt_pk_bf16_f32
  __bf16 h = (__bf16)f; return __builtin_bit_cast(u16, h);
}
__device__ inline bf16x8 ld_frag(const u16* p) {
  return __builtin_bit_cast(bf16x8, *(const u16x8*)p);
}
__device__ inline void dma16(const u16* g, u16* l) {
  __builtin_amdgcn_global_load_lds(
      (const __attribute__((address_space(1))) unsigned*)g,
      (__attribute__((address_space(3))) unsigned*)l, 16, 0, 0);
}

#if __has_builtin(__builtin_amdgcn_exp2f)
#define EXP2(x) __builtin_amdgcn_exp2f(x)
#else
#define EXP2(x) exp2f(x)
#endif

// ---------------------------------------------------------------------------
// Merged prep: blocks [0,1024): weight transpose W[k][n] fp32 -> Wt[n][k] bf16
// (wz = bid>>8, 16x16 tile grid); blocks [1024,4096): input fp32->bf16 convert
// (az = (bid-1024)>>10).  One launch replaces prep_w + prep_a.
// ---------------------------------------------------------------------------
__launch_bounds__(256)
__global__ void prep(const float* __restrict__ Wq, const float* __restrict__ Wk,
                     const float* __restrict__ Wv, const float* __restrict__ Wo,
                     u16* __restrict__ Wt,
                     const float* __restrict__ q, const float* __restrict__ k,
                     const float* __restrict__ v, u16* __restrict__ dq,
                     u16* __restrict__ dk, u16* __restrict__ dv) {
  const int bid = blockIdx.x;
  const int tid = threadIdx.x;
  if (bid < 1024) {
    __shared__ u16 T[64 * 72];
    const int z = bid >> 8, rem = bid & 255;
    const float* W = z == 0 ? Wq : z == 1 ? Wk : z == 2 ? Wv : Wo;
    u16* D = Wt + ((size_t)z << 20);
    const int c0 = (rem & 15) * 64, k0 = (rem >> 4) * 64;
    const int kr = tid >> 2, cs = (tid & 3) * 16;
    const float* src = W + (size_t)(k0 + kr) * 1024 + c0 + cs;
    float f[16];
#pragma unroll
    for (int i = 0; i < 4; ++i) *(float4*)&f[i * 4] = ((const float4*)src)[i];
#pragma unroll
    for (int i = 0; i < 16; ++i) T[(cs + i) * 72 + kr] = cvt_bf(f[i]);
    __syncthreads();
    const int nn = tid >> 2, ks = (tid & 3) * 16;
    u16* dst = D + (size_t)(c0 + nn) * 1024 + k0 + ks;
    *(u16x8*)dst = *(u16x8*)&T[nn * 72 + ks];
    *(u16x8*)(dst + 8) = *(u16x8*)&T[nn * 72 + ks + 8];
  } else {
    const int idx = bid - 1024;
    const int z = idx >> 10, bx = idx & 1023;
    const float* s = z == 0 ? q : z == 1 ? k : v;
    u16* d = z == 0 ? dq : z == 1 ? dk : dv;
    for (size_t i = (size_t)bx * 256 + tid; i < (size_t)1048576; i += 262144) {
      const float* g = s + i * 8;
      float4 f0 = *(const float4*)g, f1 = *(const float4*)(g + 4);
      u16x8 h;
      h[0] = cvt_bf(f0.x); h[1] = cvt_bf(f0.y); h[2] = cvt_bf(f0.z); h[3] = cvt_bf(f0.w);
      h[4] = cvt_bf(f1.x); h[5] = cvt_bf(f1.y); h[6] = cvt_bf(f1.z); h[7] = cvt_bf(f1.w);
      *(u16x8*)(d + i * 8) = h;
    }
  }
}

// ---------------------------------------------------------------------------
// QKV GEMM — 256x256 tile, BK=64, 8 waves, fine-grained 4-phase schedule
// (best measured: 94-96us, MfmaUtil 21%).  See R8 notes: counted vmcnt(2/4),
// never 0 mid-loop; chunked-linear conflict-free LDS; dbuf 128KB.
// z=0: Q=relu*QSC; z=1: K; z=2: operand-swapped -> acc=V^T, repack to Vt.
// ---------------------------------------------------------------------------
__launch_bounds__(512, 2)
__global__ void gemm_fwd(const u16* __restrict__ Aq, const u16* __restrict__ Ak,
                         const u16* __restrict__ Av, const u16* __restrict__ Wt,
                         u16* __restrict__ Qw, u16* __restrict__ Kw,
                         u16* __restrict__ Vw) {
  __shared__ u16 smem[65536];  // 128KB
  const int z = blockIdx.z;
  const u16* A = z == 0 ? Aq : z == 1 ? Ak : Av;
  const u16* Bt = Wt + ((size_t)z << 20);
  u16* out = z == 0 ? Qw : z == 1 ? Kw : Vw;
  const u16* Aop = (z == 2) ? Bt : A;
  const u16* Bop = (z == 2) ? A : Bt;

  const int tid = threadIdx.x;
  const int lane = tid & 63, l15 = lane & 15, quad = lane >> 4;
  const int wv = tid >> 6, wm = wv & 1, wn = wv >> 1;  // 2M x 4N wave grid
  const int mblk = ((blockIdx.x & 7) << 2) | (blockIdx.x >> 3);
  const int m0 = (z == 2) ? blockIdx.y * 256 : mblk * 256;
  const int n0 = (z == 2) ? mblk * 256 : blockIdx.y * 256;

  const u16* gA[2];
  const u16* gB[2];
#pragma unroll
  for (int i = 0; i < 2; ++i) {
    const int c = i * 512 + tid;
    gA[i] = Aop + (size_t)(m0 + (c & 255)) * 1024 + (c >> 8) * 8;
    gB[i] = Bop + (size_t)(n0 + (c & 255)) * 1024 + (c >> 8) * 8;
  }
  const int ub0 = (wv * 64) * 8, ub1 = (512 + wv * 64) * 8;  // wave-uniform

  const int offA = (quad * 256 + wm * 128 + l15) * 8;  // + mi*128, +8192 kk1
  const int offB = (quad * 256 + wn * 64 + l15) * 8;   // + nj*128, +8192 kk1

  f32x4 acc[8][4] = {};

#pragma unroll
  for (int h = 0; h < 2; ++h) {
    dma16(gA[0] + h * 32, &smem[h * 8192 + ub0]);
    dma16(gA[1] + h * 32, &smem[h * 8192 + ub1]);
    dma16(gB[0] + h * 32, &smem[16384 + h * 8192 + ub0]);
    dma16(gB[1] + h * 32, &smem[16384 + h * 8192 + ub1]);
  }
  asm volatile("s_waitcnt vmcnt(0)" ::: "memory");
  __builtin_amdgcn_sched_barrier(0);
  __builtin_amdgcn_s_barrier();

#pragma unroll 1
  for (int t = 0; t < 16; ++t) {
    const int pb = (t & 1) * 32768;
    const int nb = 32768 - pb;
    const u16* aB = smem + pb;
    const u16* bB = smem + pb + 16384;
    u16* nA = smem + nb;
    u16* nBf = smem + nb + 16384;
    const int adv = (t + 1) * 64;
    bf16x8 bk0[4], bk1[4], a[4];

    // ---------------- P1: kk0, mi0-3 ----------------
#pragma unroll
    for (int j = 0; j < 4; ++j) bk0[j] = ld_frag(bB + offB + j * 128);
#pragma unroll
    for (int i = 0; i < 4; ++i) a[i] = ld_frag(aB + offA + i * 128);
    if (t < 15) {
      dma16(gA[0] + adv, &nA[ub0]);
      dma16(gA[1] + adv, &nA[ub1]);
    }
    __builtin_amdgcn_s_barrier();
    asm volatile("s_waitcnt lgkmcnt(0)" ::: "memory");
    __builtin_amdgcn_sched_barrier(0);
    __builtin_amdgcn_s_setprio(1);
#pragma unroll
    for (int i = 0; i < 4; ++i)
#pragma unroll
      for (int j = 0; j < 4; ++j)
        acc[i][j] = MFMA16(a[i], bk0[j], acc[i][j]);
    __builtin_amdgcn_s_setprio(0);
    if (t < 15)
      asm volatile("s_waitcnt vmcnt(2)" ::: "memory");
    else
      asm volatile("s_waitcnt vmcnt(0)" ::: "memory");
    __builtin_amdgcn_sched_barrier(0);
    __builtin_amdgcn_s_barrier();

    // ---------------- P2: kk1, mi0-3 ----------------
#pragma unroll
    for (int j = 0; j < 4; ++j) bk1[j] = ld_frag(bB + offB + 8192 + j * 128);
#pragma unroll
    for (int i = 0; i < 4; ++i) a[i] = ld_frag(aB + offA + 8192 + i * 128);
    if (t < 15) {
      dma16(gB[0] + adv, &nBf[ub0]);
      dma16(gB[1] + adv, &nBf[ub1]);
    }
    __builtin_amdgcn_s_barrier();
    asm volatile("s_waitcnt lgkmcnt(0)" ::: "memory");
    __builtin_amdgcn_sched_barrier(0);
    __builtin_amdgcn_s_setprio(1);
#pragma unroll
    for (int i = 0; i < 4; ++i)
#pragma unroll
      for (int j = 0; j < 4; ++j)
        acc[i][j] = MFMA16(a[i], bk1[j], acc[i][j]);
    __builtin_amdgcn_s_setprio(0);
    __builtin_amdgcn_s_barrier();

    // ---------------- P3: kk0, mi4-7 (b kk0 reused) ----------------
#pragma unroll
    for (int i = 0; i < 4; ++i) a[i] = ld_frag(aB + offA + (4 + i) * 128);
    if (t < 15) {
      dma16(gA[0] + adv + 32, &nA[8192 + ub0]);
      dma16(gA[1] + adv + 32, &nA[8192 + ub1]);
    }
    __builtin_amdgcn_s_barrier();
    asm volatile("s_waitcnt lgkmcnt(0)" ::: "memory");
    __builtin_amdgcn_sched_barrier(0);
    __builtin_amdgcn_s_setprio(1);
#pragma unroll
    for (int i = 0; i < 4; ++i)
#pragma unroll
      for (int j = 0; j < 4; ++j)
        acc[4 + i][j] = MFMA16(a[i], bk0[j], acc[4 + i][j]);
    __builtin_amdgcn_s_setprio(0);
    __builtin_amdgcn_s_barrier();

    // ---------------- P4: kk1, mi4-7 (b kk1 reused) ----------------
#pragma unroll
    for (int i = 0; i < 4; ++i) a[i] = ld_frag(aB + offA + 8192 + (4 + i) * 128);
    if (t < 15) {
      dma16(gB[0] + adv + 32, &nBf[8192 + ub0]);
      dma16(gB[1] + adv + 32, &nBf[8192 + ub1]);
    }
    __builtin_amdgcn_s_barrier();
    asm volatile("s_waitcnt lgkmcnt(0)" ::: "memory");
    __builtin_amdgcn_sched_barrier(0);
    __builtin_amdgcn_s_setprio(1);
#pragma unroll
    for (int i = 0; i < 4; ++i)
#pragma unroll
      for (int j = 0; j < 4; ++j)
        acc[4 + i][j] = MFMA16(a[i], bk1[j], acc[4 + i][j]);
    __builtin_amdgcn_s_setprio(0);
    if (t < 15) {
      asm volatile("s_waitcnt vmcnt(4)" ::: "memory");
      __builtin_amdgcn_sched_barrier(0);
    }
    __builtin_amdgcn_s_barrier();
  }

  if (z < 2) {
    const float sc = z == 0 ? QSC : 1.0f;
#pragma unroll
    for (int i = 0; i < 8; ++i)
#pragma unroll
      for (int j = 0; j < 4; ++j)
#pragma unroll
        for (int r = 0; r < 4; ++r) {
          float v = fmaxf(acc[i][j][r], 0.f) * sc;
          int m = m0 + wm * 128 + i * 16 + quad * 4 + r;
          int n = n0 + wn * 64 + j * 16 + l15;
          out[(size_t)m * 1024 + n] = f2bf(v);
        }
  } else {
    const int bb = n0 >> 11, s0 = n0 & 2047;
#pragma unroll
    for (int half = 0; half < 2; ++half) {
      __syncthreads();
      if ((wn >> 1) == half) {
#pragma unroll
        for (int i = 0; i < 8; ++i)
#pragma unroll
          for (int j = 0; j < 4; ++j)
#pragma unroll
            for (int r = 0; r < 4; ++r) {
              const int row = wm * 128 + i * 16 + quad * 4 + r;
              const int col = (wn & 1) * 64 + j * 16 + l15;
              smem[row * 128 + col] = f2bf(fmaxf(acc[i][j][r], 0.f));
            }
      }
      __syncthreads();
#pragma unroll
      for (int i2 = 0; i2 < 8; ++i2) {
        const int c = i2 * 512 + tid;
        const int row = c >> 4, ch = c & 15;
        u16* dst = out + (size_t)(bb * 1024 + m0 + row) * 2048 + s0 +
                   half * 128 + ch * 8;
        *(u16x8*)dst = *(u16x8*)&smem[row * 128 + ch * 8];
      }
    }
  }
}

// ---------------------------------------------------------------------------
// Output GEMM: relu(ctx @ Wo), fp32 out — 256x128 tile, BK=64, 4 waves,
// minimum-2-phase step.  96KB dbuf LDS, grid 32x8 = 256 blocks = 1/CU.
// ---------------------------------------------------------------------------
__launch_bounds__(256, 2)
__global__ void gemm_out(const u16* __restrict__ A, const u16* __restrict__ Bt,
                         float* __restrict__ out) {
  __shared__ u16 smem[49152];  // 96KB: 2 bufs x (A 16384 u16 | B 8192 u16)
  const int tid = threadIdx.x;
  const int lane = tid & 63, l15 = lane & 15, quad = lane >> 4;
  const int wv = tid >> 6, wm = wv & 1, wn = wv >> 1;
  const int mblk = ((blockIdx.x & 7) << 2) | (blockIdx.x >> 3);
  const int m0 = mblk * 256;
  const int n0 = blockIdx.y * 128;

  const u16* gA[8];
#pragma unroll
  for (int i = 0; i < 8; ++i) {
    const int c = i * 256 + tid;
    gA[i] = A + (size_t)(m0 + (c & 255)) * 1024 + (c >> 8) * 8;
  }
  const u16* gB[4];
#pragma unroll
  for (int i = 0; i < 4; ++i) {
    const int c = i * 256 + tid;
    gB[i] = Bt + (size_t)(n0 + (c & 127)) * 1024 + (c >> 7) * 8;
  }

  const int offA = (quad * 256 + wm * 128 + l15) * 8;          // +8192 for kk1
  const int offB = 16384 + (quad * 128 + wn * 64 + l15) * 8;   // +4096 for kk1

  f32x4 acc[8][4] = {};

#pragma unroll
  for (int i = 0; i < 8; ++i) dma16(gA[i], &smem[i * 2048 + wv * 512]);
#pragma unroll
  for (int i = 0; i < 4; ++i) dma16(gB[i], &smem[16384 + i * 2048 + wv * 512]);
  asm volatile("s_waitcnt vmcnt(0)" ::: "memory");
  __builtin_amdgcn_sched_barrier(0);
  __builtin_amdgcn_s_barrier();

#pragma unroll 1
  for (int t = 0; t < 16; ++t) {
    const int bo = (t & 1) ? 24576 : 0;
    const int nbo = bo ^ 24576;
    bf16x8 a[4], b[4];
    if (t < 15) {
#pragma unroll
      for (int i = 0; i < 8; ++i)
        dma16(gA[i] + (t + 1) * 64, &smem[nbo + i * 2048 + wv * 512]);
    }
#pragma unroll
    for (int j = 0; j < 4; ++j) b[j] = ld_frag(&smem[bo + offB + j * 128]);
#pragma unroll
    for (int i = 0; i < 4; ++i) a[i] = ld_frag(&smem[bo + offA + i * 128]);
    asm volatile("s_waitcnt lgkmcnt(0)" ::: "memory");
    __builtin_amdgcn_sched_barrier(0);
    __builtin_amdgcn_s_setprio(1);
#pragma unroll
    for (int i = 0; i < 4; ++i)
#pragma unroll
      for (int j = 0; j < 4; ++j)
        acc[i][j] = MFMA16(a[i], b[j], acc[i][j]);
    __builtin_amdgcn_s_setprio(0);
#pragma unroll
    for (int i = 0; i < 4; ++i)
      a[i] = ld_frag(&smem[bo + offA + (4 + i) * 128]);
    asm volatile("s_waitcnt lgkmcnt(0)" ::: "memory");
    __builtin_amdgcn_sched_barrier(0);
    __builtin_amdgcn_s_setprio(1);
#pragma unroll
    for (int i = 0; i < 4; ++i)
#pragma unroll
      for (int j = 0; j < 4; ++j)
        acc[4 + i][j] = MFMA16(a[i], b[j], acc[4 + i][j]);
    __builtin_amdgcn_s_setprio(0);
    if (t < 15) {
#pragma unroll
      for (int i = 0; i < 4; ++i)
        dma16(gB[i] + (t + 1) * 64, &smem[nbo + 16384 + i * 2048 + wv * 512]);
    }
#pragma unroll
    for (int j = 0; j < 4; ++j)
      b[j] = ld_frag(&smem[bo + offB + 4096 + j * 128]);
#pragma unroll
    for (int i = 0; i < 4; ++i)
      a[i] = ld_frag(&smem[bo + offA + 8192 + i * 128]);
    asm volatile("s_waitcnt lgkmcnt(0)" ::: "memory");
    __builtin_amdgcn_sched_barrier(0);
    __builtin_amdgcn_s_setprio(1);
#pragma unroll
    for (int i = 0; i < 4; ++i)
#pragma unroll
      for (int j = 0; j < 4; ++j)
        acc[i][j] = MFMA16(a[i], b[j], acc[i][j]);
    __builtin_amdgcn_s_setprio(0);
#pragma unroll
    for (int i = 0; i < 4; ++i)
      a[i] = ld_frag(&smem[bo + offA + 8192 + (4 + i) * 128]);
    asm volatile("s_waitcnt lgkmcnt(0)" ::: "memory");
    __builtin_amdgcn_sched_barrier(0);
    __builtin_amdgcn_s_setprio(1);
#pragma unroll
    for (int i = 0; i < 4; ++i)
#pragma unroll
      for (int j = 0; j < 4; ++j)
        acc[4 + i][j] = MFMA16(a[i], b[j], acc[4 + i][j]);
    __builtin_amdgcn_s_setprio(0);
    if (t < 15) {
      asm volatile("s_waitcnt vmcnt(0)" ::: "memory");
      __builtin_amdgcn_sched_barrier(0);
    }
    __builtin_amdgcn_s_barrier();
  }

#pragma unroll
  for (int i = 0; i < 8; ++i)
#pragma unroll
    for (int j = 0; j < 4; ++j)
#pragma unroll
      for (int r = 0; r < 4; ++r) {
        int m = m0 + wm * 128 + i * 16 + quad * 4 + r;
        int n = n0 + wn * 64 + j * 16 + l15;
        out[(size_t)m * 1024 + n] = fmaxf(acc[i][j][r], 0.f);
      }
}

// ---------------------------------------------------------------------------
// Flash attention v10 — v9 + ls via ones-column MFMA:
//   lsa[qh] = MFMA16(ones, pa[qh], lsa[qh])  (A=ones -> out[d][q] = sum_k P)
// rides the matrix pipe inside the existing PV cluster; removes 48 f32
// adds/tile/thread AND the final cross-lane shfl reduce (sum over all 64
// keys/tile completes inside the MFMA; every acc row holds ls(q=l15)).
// 64 q rows per wave (qh=4), 256 q/block, grid (64,8)=512 = exactly 2/CU.
// ---------------------------------------------------------------------------
__launch_bounds__(256, 2)
__global__ void attn(const u16* __restrict__ Q, const u16* __restrict__ K,
                     const u16* __restrict__ V, u16* __restrict__ ctx) {
  __shared__ u16 Ksm[2][4096];  // chunks [dc(8)][key(64)] x 8 u16 (8KB/buf)
  __shared__ u16 Vsm[2][4096];  // chunks [kc(8)][d(64)]  x 8 u16
  __shared__ u16 Psm[4][4096];  // per-wave chunks [kc(8)][q(64)] x 8 u16

  const int tid = threadIdx.x;
  const int lane = tid & 63, l15 = lane & 15, quad = lane >> 4;
  const int wv = tid >> 6;
  const int bh = blockIdx.x, b = bh >> 4, h = bh & 15;
  const int q0 = blockIdx.y * 256 + wv * 64;

  const u16* Kb = K + ((size_t)b * 2048) * 1024 + h * 64;
  const u16* Vb = V + (size_t)bh * 64 * 2048;
  u16* Pw = Psm[wv];

  const int ck0 = tid, ck1 = 256 + tid;
  const u16* kg0 = Kb + (size_t)(ck0 & 63) * 1024 + (ck0 >> 6) * 8;
  const u16* kg1 = Kb + (size_t)(ck1 & 63) * 1024 + (ck1 >> 6) * 8;
  const u16* vg0 = Vb + (size_t)(ck0 & 63) * 2048 + (ck0 >> 6) * 8;
  const u16* vg1 = Vb + (size_t)(ck1 & 63) * 2048 + (ck1 >> 6) * 8;

  // Q B-frags (pre-scaled by 0.125*log2e), resident all kernel (32 VGPR)
  bf16x8 aq[4][2];
#pragma unroll
  for (int qh = 0; qh < 4; ++qh)
#pragma unroll
    for (int kk = 0; kk < 2; ++kk)
      aq[qh][kk] = ld_frag(Q + (size_t)(b * 2048 + q0 + qh * 16 + l15) * 1024 +
                           h * 64 + kk * 32 + quad * 8);

  // ones A-frag for ls row-sum MFMA (bf16 1.0 = 0x3F80)
  u16x8 ones16;
#pragma unroll
  for (int i = 0; i < 8; ++i) ones16[i] = 0x3F80;
  const bf16x8 ones = __builtin_bit_cast(bf16x8, ones16);

  f32x4 o[4][4] = {};
  f32x4 lsa[4] = {};

  dma16(kg0, &Ksm[0][ck0 * 8]);
  dma16(kg1, &Ksm[0][ck1 * 8]);
  dma16(vg0, &Vsm[0][ck0 * 8]);
  dma16(vg1, &Vsm[0][ck1 * 8]);

#pragma unroll 1
  for (int t = 0; t < 32; ++t) {
    const int cur = t & 1, nxt = cur ^ 1;
    __syncthreads();  // drains tile-t DMA (vmcnt) + prior tile's LDS reads (WAR)

    if (t + 1 < 32) {
      const int kadv = (t + 1) * 64;
      dma16(kg0 + (size_t)kadv * 1024, &Ksm[nxt][ck0 * 8]);
      dma16(kg1 + (size_t)kadv * 1024, &Ksm[nxt][ck1 * 8]);
      dma16(vg0 + kadv, &Vsm[nxt][ck0 * 8]);
      dma16(vg1 + kadv, &Vsm[nxt][ck1 * 8]);
    }

    bf16x8 kf[2][4];
#pragma unroll
    for (int kk = 0; kk < 2; ++kk)
#pragma unroll
      for (int jj = 0; jj < 4; ++jj)
        kf[kk][jj] = ld_frag(&Ksm[cur][((kk * 4 + quad) * 64 + jj * 16 + l15) * 8]);

    f32x4 st[4][4] = {};
    asm volatile("s_waitcnt lgkmcnt(0)" ::: "memory");
    __builtin_amdgcn_sched_barrier(0);
    __builtin_amdgcn_s_setprio(1);
#pragma unroll
    for (int kk = 0; kk < 2; ++kk)
#pragma unroll
      for (int jj = 0; jj < 4; ++jj)
#pragma unroll
        for (int qh = 0; qh < 4; ++qh)
          st[qh][jj] = MFMA16(kf[kk][jj], aq[qh][kk], st[qh][jj]);
    __builtin_amdgcn_s_setprio(0);

    // p = exp2(st); packed cvt; chunked conflict-free P write (no scalar ls)
#pragma unroll
    for (int qh = 0; qh < 4; ++qh)
#pragma unroll
      for (int jj = 0; jj < 4; ++jj) {
        float p0 = EXP2(st[qh][jj][0]), p1 = EXP2(st[qh][jj][1]);
        float p2 = EXP2(st[qh][jj][2]), p3 = EXP2(st[qh][jj][3]);
        u16x4 pk;
        pk[0] = cvt_bf(p0); pk[1] = cvt_bf(p1);
        pk[2] = cvt_bf(p2); pk[3] = cvt_bf(p3);
        const int kc = jj * 2 + (quad >> 1);
        *(u16x4*)&Pw[(kc * 64 + qh * 16 + l15) * 8 + (quad & 1) * 4] = pk;
      }

    // pa (B-frag of P^T) and vb (A-frag of V^T) from LDS; PV + ls MFMAs
#pragma unroll
    for (int kk = 0; kk < 2; ++kk) {
      bf16x8 pa[4];
#pragma unroll
      for (int qh = 0; qh < 4; ++qh)
        pa[qh] = ld_frag(&Pw[((kk * 4 + quad) * 64 + qh * 16 + l15) * 8]);
      asm volatile("s_waitcnt lgkmcnt(0)" ::: "memory");
      __builtin_amdgcn_sched_barrier(0);
      __builtin_amdgcn_s_setprio(1);
#pragma unroll
      for (int qh = 0; qh < 4; ++qh)
        lsa[qh] = MFMA16(ones, pa[qh], lsa[qh]);
#pragma unroll
      for (int j = 0; j < 4; ++j) {
        bf16x8 vb = ld_frag(&Vsm[cur][((kk * 4 + quad) * 64 + j * 16 + l15) * 8]);
#pragma unroll
        for (int qh = 0; qh < 4; ++qh)
          o[qh][j] = MFMA16(vb, pa[qh], o[qh][j]);
      }
      __builtin_amdgcn_s_setprio(0);
    }
  }

  float inv[4];
#pragma unroll
  for (int qh = 0; qh < 4; ++qh) inv[qh] = 1.f / lsa[qh][0];

  // O^T: row = d = j*16+quad*4+r, col = q = l15 -> 8B vector ctx stores
#pragma unroll
  for (int qh = 0; qh < 4; ++qh) {
    const int tok = b * 2048 + q0 + qh * 16 + l15;
#pragma unroll
    for (int j = 0; j < 4; ++j) {
      u16x4 pk;
#pragma unroll
      for (int r = 0; r < 4; ++r) pk[r] = cvt_bf(o[qh][j][r] * inv[qh]);
      *(u16x4*)&ctx[(size_t)tok * 1024 + h * 64 + j * 16 + quad * 4] = pk;
    }
  }
}

// ---------------------------------------------------------------------------
extern "C" void kernel_launch(void* const* d_in, const int* in_sizes, int n_in,
                              void* d_out, int out_size, void* d_ws, size_t ws_size,
                              hipStream_t stream) {
  const float* query = (const float*)d_in[0];
  const float* key   = (const float*)d_in[1];
  const float* value = (const float*)d_in[2];
  const float* Wq = (const float*)d_in[3];
  const float* Wk = (const float*)d_in[4];
  const float* Wv = (const float*)d_in[5];
  const float* Wo = (const float*)d_in[6];
  float* outp = (float*)d_out;

  // ws (u16 units): Wt 4Mi | Awq 8Mi | Qw 8Mi | Kw 8Mi | Vt 8Mi = 72 MB.
  // Awk/Awv live in d_out (32 MB, consumed before gemm_out overwrites it);
  // ctx aliases Awq (consumed by gemm_fwd before attn writes it).
  u16* Wt  = (u16*)d_ws;
  u16* Awq = Wt + ((size_t)4 << 20);
  u16* Qw  = Awq + ((size_t)8 << 20);
  u16* Kw  = Qw + ((size_t)8 << 20);
  u16* Vt  = Kw + ((size_t)8 << 20);
  u16* Awk = (u16*)d_out;
  u16* Awv = Awk + ((size_t)8 << 20);
  u16* Cw  = Awq;

  prep<<<dim3(4096), 256, 0, stream>>>(Wq, Wk, Wv, Wo, Wt,
                                       query, key, value, Awq, Awk, Awv);
  gemm_fwd<<<dim3(32, 4, 3), 512, 0, stream>>>(Awq, Awk, Awv, Wt, Qw, Kw, Vt);
  attn<<<dim3(64, 8), 256, 0, stream>>>(Qw, Kw, Vt, Cw);
  gemm_out<<<dim3(32, 8), 256, 0, stream>>>(Cw, Wt + ((size_t)3 << 20), outp);
}